// Round 11
// baseline (242.656 us; speedup 1.0000x reference)
//
#include <hip/hip_runtime.h>
#include <hip/hip_bf16.h>

#define NPTS 4096
#define KNN  32

typedef __attribute__((ext_vector_type(8))) short short8;
typedef __attribute__((ext_vector_type(4))) float floatx4;
typedef unsigned short u16x2 __attribute__((ext_vector_type(2)));
typedef unsigned short u16x8 __attribute__((ext_vector_type(8)));

__device__ __forceinline__ unsigned short f2bf(float f) {
    unsigned u = __float_as_uint(f);
    u = (u + 0x7FFFu + ((u >> 16) & 1u)) >> 16;
    return (unsigned short)u;
}

// ---------------- Kernel 0: pack points + convert weights to bf16 ------------
__global__ __launch_bounds__(256) void prep_all(
    const float* __restrict__ x, float4* __restrict__ pts4,
    const float* __restrict__ gW0, const float* __restrict__ gW1,
    const float* __restrict__ mW0, const float* __restrict__ mW1,
    const float* __restrict__ sW1, const float* __restrict__ sW2,
    unsigned short* __restrict__ Wb0, unsigned short* __restrict__ Wb1,
    unsigned short* __restrict__ Wb2, unsigned short* __restrict__ Wb3,
    unsigned short* __restrict__ Wb4, unsigned short* __restrict__ Wb5)
{
    const int blk = blockIdx.x, t = threadIdx.x;
    if (blk < 64) {
        const int i = blk * 256 + t;                 // 0..16383 = b*4096+n
        const int b = i >> 12, n = i & (NPTS - 1);
        const float* xb = x + (size_t)b * 3 * NPTS;
        const float qx = xb[n], qy = xb[NPTS + n], qz = xb[2 * NPTS + n];
        pts4[i] = make_float4(qx, qy, qz, qx * qx + qy * qy + qz * qz);
    } else {
        const int wi = (blk - 64) * 256 + t;         // 0..692223 (exact)
        float v; unsigned short* dst;
        if (wi < 98304)       { v = gW0[wi];          dst = Wb0 + wi; }
        else if (wi < 360448) { v = gW1[wi - 98304];  dst = Wb1 + (wi - 98304); }
        else if (wi < 622592) { v = mW0[wi - 360448]; dst = Wb2 + (wi - 360448); }
        else if (wi < 655360) { v = mW1[wi - 622592]; dst = Wb3 + (wi - 622592); }
        else if (wi < 667648) { v = sW1[wi - 655360]; dst = Wb4 + (wi - 655360); }
        else                  { v = sW2[wi - 667648]; dst = Wb5 + (wi - 667648); }
        *dst = f2bf(v);
    }
}

// ---------------- Kernel 1: exact KNN v7 — 2 queries/block (R10-passing) -----
__global__ __launch_bounds__(256) void knn_kernel19(const float4* __restrict__ pts4,
                                                    int* __restrict__ knn_out)
{
    __shared__ unsigned sredA[2][4], sredB[2][4];
    __shared__ unsigned minSA[256], minSB[256];
    __shared__ unsigned long long CA[256], CB[256];
    __shared__ unsigned ccnt2[2];

    const int t = threadIdx.x, wid = t >> 6, lane = t & 63;
    const int pr = blockIdx.x;               // 0..8191 = b*2048 + pair
    const int b  = pr >> 11;
    const int qa = ((pr & 2047) << 1);
    const int qb = qa + 1;
    const float4* P = pts4 + ((size_t)b << 12);
    const float4 sA = P[qa];
    const float4 sB = P[qb];

    if (t < 2) ccnt2[t] = 0u;
    CA[t] = 0xFFFFFFFFFFFFFFFFULL;           // pad for fixed-64 rank (B1 orders)
    CB[t] = 0xFFFFFFFFFFFFFFFFULL;

    unsigned kA[16], kB[16];
    #pragma unroll
    for (int g = 0; g < 4; ++g) {
        float4 c0 = P[((g * 4 + 0) << 8) + t];
        float4 c1 = P[((g * 4 + 1) << 8) + t];
        float4 c2 = P[((g * 4 + 2) << 8) + t];
        float4 c3 = P[((g * 4 + 3) << 8) + t];
        float dA0 = (sA.w + c0.w) - 2.0f * (sA.x * c0.x + sA.y * c0.y + sA.z * c0.z);
        float dA1 = (sA.w + c1.w) - 2.0f * (sA.x * c1.x + sA.y * c1.y + sA.z * c1.z);
        float dA2 = (sA.w + c2.w) - 2.0f * (sA.x * c2.x + sA.y * c2.y + sA.z * c2.z);
        float dA3 = (sA.w + c3.w) - 2.0f * (sA.x * c3.x + sA.y * c3.y + sA.z * c3.z);
        float dB0 = (sB.w + c0.w) - 2.0f * (sB.x * c0.x + sB.y * c0.y + sB.z * c0.z);
        float dB1 = (sB.w + c1.w) - 2.0f * (sB.x * c1.x + sB.y * c1.y + sB.z * c1.z);
        float dB2 = (sB.w + c2.w) - 2.0f * (sB.x * c2.x + sB.y * c2.y + sB.z * c2.z);
        float dB3 = (sB.w + c3.w) - 2.0f * (sB.x * c3.x + sB.y * c3.y + sB.z * c3.z);
        unsigned uA0 = __float_as_uint(dA0), uA1 = __float_as_uint(dA1);
        unsigned uA2 = __float_as_uint(dA2), uA3 = __float_as_uint(dA3);
        unsigned uB0 = __float_as_uint(dB0), uB1 = __float_as_uint(dB1);
        unsigned uB2 = __float_as_uint(dB2), uB3 = __float_as_uint(dB3);
        kA[g * 4 + 0] = uA0 ^ (((unsigned)((int)uA0 >> 31)) | 0x80000000u);
        kA[g * 4 + 1] = uA1 ^ (((unsigned)((int)uA1 >> 31)) | 0x80000000u);
        kA[g * 4 + 2] = uA2 ^ (((unsigned)((int)uA2 >> 31)) | 0x80000000u);
        kA[g * 4 + 3] = uA3 ^ (((unsigned)((int)uA3 >> 31)) | 0x80000000u);
        kB[g * 4 + 0] = uB0 ^ (((unsigned)((int)uB0 >> 31)) | 0x80000000u);
        kB[g * 4 + 1] = uB1 ^ (((unsigned)((int)uB1 >> 31)) | 0x80000000u);
        kB[g * 4 + 2] = uB2 ^ (((unsigned)((int)uB2 >> 31)) | 0x80000000u);
        kB[g * 4 + 3] = uB3 ^ (((unsigned)((int)uB3 >> 31)) | 0x80000000u);
    }

    // per-thread mins (register-only)
    unsigned tmA = kA[0], tmB = kB[0];
    #pragma unroll
    for (int r = 1; r < 16; ++r) {
        tmA = (kA[r] < tmA) ? kA[r] : tmA;
        tmB = (kB[r] < tmB) ? kB[r] : tmB;
    }
    minSA[t] = tmA;
    minSB[t] = tmB;
    __syncthreads();                                   // B1

    // fold 256 thread-minima -> 64 lane-minima (identical across waves)
    unsigned mA = minSA[lane], mB = minSB[lane];
    {
        unsigned a1 = minSA[lane + 64], a2 = minSA[lane + 128], a3 = minSA[lane + 192];
        unsigned b1 = minSB[lane + 64], b2 = minSB[lane + 128], b3 = minSB[lane + 192];
        mA = (a1 < mA) ? a1 : mA;  a2 = (a3 < a2) ? a3 : a2;  mA = (a2 < mA) ? a2 : mA;
        mB = (b1 < mB) ? b1 : mB;  b2 = (b3 < b2) ? b3 : b2;  mB = (b2 < mB) ? b2 : mB;
    }

    // wave-local 16-round bisection on the TOP-16 BITS, both queries per round.
    const unsigned msA = mA >> 16, msB = mB >> 16;
    unsigned loA = 0u, hiA = 0xFFFFu, loB = 0u, hiB = 0xFFFFu;
    for (int i = 0; i < 16; ++i) {
        const unsigned midA = (loA + hiA) >> 1;
        const unsigned midB = (loB + hiB) >> 1;
        const unsigned cA = (unsigned)__popcll(__ballot(msA <= midA));
        const unsigned cB = (unsigned)__popcll(__ballot(msB <= midB));
        if (cA >= 33u) hiA = midA; else loA = midA + 1u;
        if (cB >= 33u) hiB = midB; else loB = midB + 1u;
    }
    const unsigned thrA = (hiA << 16) | 0xFFFFu;
    const unsigned thrB = (hiB << 16) | 0xFFFFu;

    // speculative compaction for both queries (resets/prefill ordered by B1)
    #pragma unroll
    for (int r = 0; r < 16; ++r) {
        if (kA[r] <= thrA) {
            unsigned p = atomicAdd(&ccnt2[0], 1u);
            if (p < 256u)
                CA[p] = ((unsigned long long)kA[r] << 32) | (unsigned)((r << 8) + t);
        }
        if (kB[r] <= thrB) {
            unsigned p = atomicAdd(&ccnt2[1], 1u);
            if (p < 256u)
                CB[p] = ((unsigned long long)kB[r] << 32) | (unsigned)((r << 8) + t);
        }
    }
    __syncthreads();                                   // B2

    int ncA = (int)ccnt2[0];
    int ncB = (int)ccnt2[1];
    bool fell_back = false;
    if (ncA > 256 || ncB > 256) {
        // ---- rare fallback: dual bisection (block-uniform) + recompaction ----
        fell_back = true;
        if (t < 2) ccnt2[t] = 0u;      // ordered before reuse by loop barriers
        int pp = 0;
        auto countLE2 = [&](unsigned ta, unsigned tb, unsigned& ga, unsigned& gb) {
            unsigned ca = 0, cb = 0;
            #pragma unroll
            for (int r = 0; r < 16; ++r) {
                ca += (unsigned)__popcll(__ballot(kA[r] <= ta));
                cb += (unsigned)__popcll(__ballot(kB[r] <= tb));
            }
            if (lane == 0) { sredA[pp & 1][wid] = ca; sredB[pp & 1][wid] = cb; }
            __syncthreads();
            ga = sredA[pp & 1][0] + sredA[pp & 1][1] +
                 sredA[pp & 1][2] + sredA[pp & 1][3];
            gb = sredB[pp & 1][0] + sredB[pp & 1][1] +
                 sredB[pp & 1][2] + sredB[pp & 1][3];
            ++pp;
        };
        unsigned lo2A = 0x100u, hi2A = 0x1FEu, cHiA = 4096u;
        unsigned lo2B = 0x100u, hi2B = 0x1FEu, cHiB = 4096u;
        for (int it = 0; it < 8; ++it) {
            const unsigned mAe = (lo2A + hi2A) >> 1;
            const unsigned mBe = (lo2B + hi2B) >> 1;
            unsigned ga, gb;
            countLE2((mAe << 23) | 0x7FFFFFu, (mBe << 23) | 0x7FFFFFu, ga, gb);
            if (ga >= 33u) { hi2A = mAe; cHiA = ga; } else lo2A = mAe + 1u;
            if (gb >= 33u) { hi2B = mBe; cHiB = gb; } else lo2B = mBe + 1u;
        }
        unsigned loKA = lo2A << 23, hiKA = (lo2A << 23) | 0x7FFFFFu, cFA = cHiA;
        unsigned loKB = lo2B << 23, hiKB = (lo2B << 23) | 0x7FFFFFu, cFB = cHiB;
        while (((cFA > 256u) && (loKA < hiKA)) || ((cFB > 256u) && (loKB < hiKB))) {
            const bool nAx = (cFA > 256u) && (loKA < hiKA);
            const bool nBx = (cFB > 256u) && (loKB < hiKB);
            const unsigned mAk = nAx ? (loKA + ((hiKA - loKA) >> 1)) : hiKA;
            const unsigned mBk = nBx ? (loKB + ((hiKB - loKB) >> 1)) : hiKB;
            unsigned ga, gb;
            countLE2(mAk, mBk, ga, gb);
            if (nAx) { if (ga >= 33u) { hiKA = mAk; cFA = ga; } else loKA = mAk + 1u; }
            if (nBx) { if (gb >= 33u) { hiKB = mBk; cFB = gb; } else loKB = mBk + 1u; }
        }
        const unsigned tFA = hiKA, tFB = hiKB;
        #pragma unroll
        for (int r = 0; r < 16; ++r) {
            if (kA[r] <= tFA) {
                unsigned p = atomicAdd(&ccnt2[0], 1u);
                if (p < 256u)
                    CA[p] = ((unsigned long long)kA[r] << 32) | (unsigned)((r << 8) + t);
            }
            if (kB[r] <= tFB) {
                unsigned p = atomicAdd(&ccnt2[1], 1u);
                if (p < 256u)
                    CB[p] = ((unsigned long long)kB[r] << 32) | (unsigned)((r << 8) + t);
            }
        }
        __syncthreads();
        ncA = (int)ccnt2[0]; if (ncA > 256) ncA = 256;
        ncB = (int)ccnt2[1]; if (ncB > 256) ncB = 256;
    }

    // rank (key,id) lexicographic — identical tie-break to JAX top_k.
    if (!fell_back && ncA <= 64 && ncB <= 64) {
        if (t < 64) {
            const unsigned long long me = CA[t];
            int rank = 0;
            #pragma unroll
            for (int j = 0; j < 64; ++j) rank += (CA[j] < me) ? 1 : 0;
            if (rank >= 1 && rank <= KNN)
                knn_out[((size_t)((b << 12) + qa)) * KNN + (rank - 1)] =
                    (int)(me & 0xFFFFFFFFu);
        } else if (t < 128) {
            const int tb = t - 64;
            const unsigned long long me = CB[tb];
            int rank = 0;
            #pragma unroll
            for (int j = 0; j < 64; ++j) rank += (CB[j] < me) ? 1 : 0;
            if (rank >= 1 && rank <= KNN)
                knn_out[((size_t)((b << 12) + qb)) * KNN + (rank - 1)] =
                    (int)(me & 0xFFFFFFFFu);
        }
    } else {
        if (t < ncA) {
            const unsigned long long me = CA[t];
            int rank = 0;
            for (int j = 0; j < ncA; ++j) rank += (CA[j] < me) ? 1 : 0;
            if (rank >= 1 && rank <= KNN)
                knn_out[((size_t)((b << 12) + qa)) * KNN + (rank - 1)] =
                    (int)(me & 0xFFFFFFFFu);
        }
        if (t < ncB) {
            const unsigned long long me = CB[t];
            int rank = 0;
            for (int j = 0; j < ncB; ++j) rank += (CB[j] < me) ? 1 : 0;
            if (rank >= 1 && rank <= KNN)
                knn_out[((size_t)((b << 12) + qb)) * KNN + (rank - 1)] =
                    (int)(me & 0xFFFFFFFFu);
        }
    }
}

// ---------------- Kernel 2: per-point MLP, layers 2-3 on MFMA (proven) -------
__global__ __launch_bounds__(256) void pointmlp_mfma(
    const float* __restrict__ x,
    const float* __restrict__ sW0, const float* __restrict__ sb0,
    const unsigned short* __restrict__ W1b, const float* __restrict__ sb1,
    const unsigned short* __restrict__ W2b, const float* __restrict__ sb2,
    unsigned short* __restrict__ F)
{
    __shared__ __align__(16) unsigned short W1s[64 * 72];
    __shared__ __align__(16) unsigned short W2s[128 * 72];
    __shared__ __align__(16) unsigned short h0T[32 * 72];
    __shared__ __align__(16) unsigned short h1T[32 * 72];
    __shared__ float W0s[192];
    __shared__ float b0s[64], b1s[64], b2s[128];
    __shared__ float pts[3 * 33];

    const int t = threadIdx.x;
    const int s = blockIdx.y;
    const int tile = blockIdx.x;
    const int b = tile >> 7;
    const int j0 = (tile & 127) << 5;
    const float* xb = x + (size_t)b * 3 * NPTS;

    if (t < 192) W0s[t] = sW0[s * 192 + t];
    if (t < 64) b0s[t] = sb0[s * 64 + t];
    if (t >= 64 && t < 128) b1s[t - 64] = sb1[s * 64 + (t - 64)];
    if (t < 128) b2s[t] = sb2[s * 128 + t];
    if (t < 96) { int c = t >> 5, p = t & 31; pts[c * 33 + p] = xb[c * NPTS + j0 + p]; }
    {   // W1 64x64 bf16 -> LDS [o][i] pad 72
        const int o = t & 63, qq = t >> 6;
        const unsigned short* src = W1b + (size_t)s * 4096 + o * 64 + qq * 16;
        *(uint4*)&W1s[o * 72 + qq * 16]     = *(const uint4*)src;
        *(uint4*)&W1s[o * 72 + qq * 16 + 8] = *(const uint4*)(src + 8);
    }
    {   // W2 128x64 bf16 -> LDS [o2][i] pad 72
        const int o2 = t & 127, hh = t >> 7;
        const unsigned short* src = W2b + (size_t)s * 8192 + o2 * 64 + hh * 32;
        *(uint4*)&W2s[o2 * 72 + hh * 32]      = *(const uint4*)src;
        *(uint4*)&W2s[o2 * 72 + hh * 32 + 8]  = *(const uint4*)(src + 8);
        *(uint4*)&W2s[o2 * 72 + hh * 32 + 16] = *(const uint4*)(src + 16);
        *(uint4*)&W2s[o2 * 72 + hh * 32 + 24] = *(const uint4*)(src + 24);
    }
    __syncthreads();

    {   // layer 1 (fp32): h0T[p][og*8..+7]
        const int p = t & 31, og = t >> 5;
        const float xx = pts[p], yy = pts[33 + p], zz = pts[66 + p];
        unsigned short hv[8];
        #pragma unroll
        for (int r = 0; r < 8; ++r) {
            const int o = og * 8 + r;
            float a = b0s[o] + W0s[o * 3] * xx + W0s[o * 3 + 1] * yy
                    + W0s[o * 3 + 2] * zz;
            hv[r] = f2bf(fmaxf(a, 0.0f));
        }
        *(uint4*)&h0T[p * 72 + og * 8] = *(const uint4*)hv;
    }
    __syncthreads();

    const int w = t >> 6, lane = t & 63, quad = lane >> 4, l15 = lane & 15;

    {   // layer 2: wave w owns m-tile w*16; ni over 2 n-tiles
        #pragma unroll
        for (int ni = 0; ni < 2; ++ni) {
            floatx4 acc = (floatx4){0.f, 0.f, 0.f, 0.f};
            #pragma unroll
            for (int k0 = 0; k0 < 2; ++k0) {
                short8 aF = *(const short8*)&W1s[(w * 16 + l15) * 72 + k0 * 32 + quad * 8];
                short8 bF = *(const short8*)&h0T[(ni * 16 + l15) * 72 + k0 * 32 + quad * 8];
                acc = __builtin_amdgcn_mfma_f32_16x16x32_bf16(aF, bF, acc, 0, 0, 0);
            }
            const int m0 = w * 16 + quad * 4;
            const int p = ni * 16 + l15;
            ushort4 pk;
            pk.x = f2bf(fmaxf(acc[0] + b1s[m0 + 0], 0.f));
            pk.y = f2bf(fmaxf(acc[1] + b1s[m0 + 1], 0.f));
            pk.z = f2bf(fmaxf(acc[2] + b1s[m0 + 2], 0.f));
            pk.w = f2bf(fmaxf(acc[3] + b1s[m0 + 3], 0.f));
            *(ushort4*)&h1T[p * 72 + m0] = pk;
        }
    }
    __syncthreads();

    {   // layer 3: wave w owns m-tiles w*2, w*2+1
        #pragma unroll
        for (int mi = 0; mi < 2; ++mi) {
            const int m0 = (w * 2 + mi) * 16;
            #pragma unroll
            for (int ni = 0; ni < 2; ++ni) {
                floatx4 acc = (floatx4){0.f, 0.f, 0.f, 0.f};
                #pragma unroll
                for (int k0 = 0; k0 < 2; ++k0) {
                    short8 aF = *(const short8*)&W2s[(m0 + l15) * 72 + k0 * 32 + quad * 8];
                    short8 bF = *(const short8*)&h1T[(ni * 16 + l15) * 72 + k0 * 32 + quad * 8];
                    acc = __builtin_amdgcn_mfma_f32_16x16x32_bf16(aF, bF, acc, 0, 0, 0);
                }
                const int o2 = m0 + quad * 4;
                const int j = j0 + ni * 16 + l15;
                ushort4 pk;
                pk.x = f2bf(fmaxf(acc[0] + b2s[o2 + 0], 0.f));
                pk.y = f2bf(fmaxf(acc[1] + b2s[o2 + 1], 0.f));
                pk.z = f2bf(fmaxf(acc[2] + b2s[o2 + 2], 0.f));
                pk.w = f2bf(fmaxf(acc[3] + b2s[o2 + 3], 0.f));
                *(ushort4*)&F[((size_t)b * NPTS + j) * 384 + s * 128 + o2] = pk;
            }
        }
    }
}

// ---------------- Kernel 3: gather-max v2 — 16B loads, 4 queries/block -------
// Previous version: 192 lanes x 4 B per neighbor row (u16x2) = 4x more VMEM
// instructions than needed. Now 48 lanes x 16 B (u16x8) cover one 768 B row;
// 192-thread block = 4 queries. Same bytes, 1/4 the loads, still perfectly
// coalesced. Unsigned elementwise max is exact for post-ReLU bf16 (all >= 0,
// monotone encoding) — same argument as the passing u16x2 version.
__global__ __launch_bounds__(192) void maxgather_bf16(
    const unsigned short* __restrict__ F, const int* __restrict__ knn,
    unsigned short* __restrict__ pt)
{
    __shared__ int idxS[4 * KNN];
    const int q0 = blockIdx.x * 4;       // 4096 blocks: queries q0..q0+3
    const int b = q0 >> 12;
    const int t = threadIdx.x;
    if (t < 4 * KNN)
        idxS[t] = knn[(size_t)(q0 + (t >> 5)) * KNN + (t & 31)];
    __syncthreads();
    const int sub = t / 48;              // query within block 0..3
    const int ln  = t % 48;              // 16-byte lane within row
    const int* idx = idxS + sub * KNN;
    const unsigned short* Fb = F + (size_t)b * NPTS * 384 + ln * 8;
    u16x8 m = (u16x8)0;
    #pragma unroll 8
    for (int k = 0; k < KNN; ++k) {
        u16x8 v = *(const u16x8*)(Fb + (size_t)idx[k] * 384);
        m = __builtin_elementwise_max(m, v);
    }
    *(u16x8*)(pt + (size_t)(q0 + sub) * 384 + ln * 8) = m;
}

// ---------------- Kernel 4: bf16 MFMA GEMM + bias + relu (R10-passing) -------
template<int DO_ROWMAX>
__global__ __launch_bounds__(256) void gemm_bf16(
    const unsigned short* __restrict__ Wb, const unsigned short* __restrict__ Bt,
    const float* __restrict__ bias, void* __restrict__ outp,
    float* __restrict__ gfeat, int M, int K)
{
    __shared__ __align__(16) unsigned short As[128 * 40];
    __shared__ __align__(16) unsigned short Bs[128 * 40];
    __shared__ float biasS[128];
    __shared__ int redI[128];

    const int t = threadIdx.x;
    const int b = blockIdx.z;
    const int m0 = blockIdx.x * 128;
    const int n0 = blockIdx.y * 128;
    if (t < 128) biasS[t] = bias[m0 + t];
    if (DO_ROWMAX && t < 128) redI[t] = 0;

    const int wave = t >> 6, lane = t & 63, quad = lane >> 4, l15 = lane & 15;
    const int wr = wave >> 1, wc = wave & 1;

    const int am = t & 127, akh = t >> 7;
    const unsigned short* Wp = Wb + (size_t)(m0 + am) * K + akh * 16;
    const int bn = t >> 2, bq = t & 3;
    const unsigned short* Bp = Bt + ((size_t)b * NPTS + n0) * K;

    floatx4 acc[16];
    #pragma unroll
    for (int i = 0; i < 16; ++i) acc[i] = (floatx4){0.f, 0.f, 0.f, 0.f};

    const int nk = K >> 5;
    for (int kt = 0; kt < nk; ++kt) {
        const int k0 = kt << 5;
        uint4 av0 = *(const uint4*)(Wp + k0);
        uint4 av1 = *(const uint4*)(Wp + k0 + 8);
        uint4 bv0 = *(const uint4*)(Bp + (size_t)bn * K + k0 + bq * 8);
        uint4 bv1 = *(const uint4*)(Bp + (size_t)(bn + 64) * K + k0 + bq * 8);
        __syncthreads();
        {
            uint4* dst = (uint4*)&As[am * 40 + akh * 16];
            dst[0] = av0;
            dst[1] = av1;
            *(uint4*)&Bs[bn * 40 + bq * 8] = bv0;
            *(uint4*)&Bs[(bn + 64) * 40 + bq * 8] = bv1;
        }
        __syncthreads();
        short8 af[4], bfv[4];
        #pragma unroll
        for (int i = 0; i < 4; ++i)
            af[i] = *(const short8*)&As[(wr * 64 + i * 16 + l15) * 40 + quad * 8];
        #pragma unroll
        for (int j = 0; j < 4; ++j)
            bfv[j] = *(const short8*)&Bs[(wc * 64 + j * 16 + l15) * 40 + quad * 8];
        #pragma unroll
        for (int i = 0; i < 4; ++i)
            #pragma unroll
            for (int j = 0; j < 4; ++j)
                acc[i * 4 + j] = __builtin_amdgcn_mfma_f32_16x16x32_bf16(
                    af[i], bfv[j], acc[i * 4 + j], 0, 0, 0);
    }

    #pragma unroll
    for (int i = 0; i < 4; ++i) {
        const int mbase = wr * 64 + i * 16 + quad * 4;
        float rm0 = 0.f, rm1 = 0.f, rm2 = 0.f, rm3 = 0.f;
        #pragma unroll
        for (int j = 0; j < 4; ++j) {
            const int n = n0 + wc * 64 + j * 16 + l15;
            float v0 = fmaxf(acc[i * 4 + j][0] + biasS[mbase + 0], 0.f);
            float v1 = fmaxf(acc[i * 4 + j][1] + biasS[mbase + 1], 0.f);
            float v2 = fmaxf(acc[i * 4 + j][2] + biasS[mbase + 2], 0.f);
            float v3 = fmaxf(acc[i * 4 + j][3] + biasS[mbase + 3], 0.f);
            if (DO_ROWMAX) {
                rm0 = fmaxf(rm0, v0); rm1 = fmaxf(rm1, v1);
                rm2 = fmaxf(rm2, v2); rm3 = fmaxf(rm3, v3);
            }
            ushort4 pk;
            pk.x = f2bf(v0); pk.y = f2bf(v1); pk.z = f2bf(v2); pk.w = f2bf(v3);
            *(ushort4*)((unsigned short*)outp +
                        ((size_t)b * NPTS + n) * M + m0 + mbase) = pk;
        }
        if (DO_ROWMAX) {
            atomicMax(&redI[mbase + 0], __float_as_int(rm0));
            atomicMax(&redI[mbase + 1], __float_as_int(rm1));
            atomicMax(&redI[mbase + 2], __float_as_int(rm2));
            atomicMax(&redI[mbase + 3], __float_as_int(rm3));
        }
    }
    if (DO_ROWMAX) {
        __syncthreads();
        if (t < 128)
            atomicMax((int*)&gfeat[(size_t)b * 1024 + m0 + t], redI[t]);
    }
}

// ---------------- Kernel 5: fused head = gemm3 + gemm4 (R4-passing, n=64) ----
__global__ __launch_bounds__(256) void fused_head(
    const unsigned short* __restrict__ Wb2, const unsigned short* __restrict__ Wb3,
    const float* __restrict__ mb0, const float* __restrict__ mb1,
    const unsigned short* __restrict__ gft, float* __restrict__ outp)
{
    __shared__ __align__(16) unsigned short As[256 * 40];
    __shared__ __align__(16) unsigned short Bs[64 * 40];
    __shared__ __align__(16) unsigned short H[64 * 264];
    __shared__ float b0s[256];
    __shared__ float b1s[128];

    const int t = threadIdx.x;
    const int n0 = blockIdx.x * 64;
    const int b = blockIdx.y;
    b0s[t] = mb0[t];
    if (t < 128) b1s[t] = mb1[t];

    const int wave = t >> 6, lane = t & 63, quad = lane >> 4, l15 = lane & 15;

    const unsigned short* Ap = Wb2 + (size_t)t * 1024;
    const int bn = t >> 2, bq = t & 3;
    const unsigned short* Bp = gft + ((size_t)b * NPTS + n0) * 1024;

    floatx4 acc[16];
    #pragma unroll
    for (int i = 0; i < 16; ++i) acc[i] = (floatx4){0.f, 0.f, 0.f, 0.f};

    for (int kt = 0; kt < 32; ++kt) {
        const int k0 = kt << 5;
        uint4 a0 = *(const uint4*)(Ap + k0);
        uint4 a1 = *(const uint4*)(Ap + k0 + 8);
        uint4 a2 = *(const uint4*)(Ap + k0 + 16);
        uint4 a3 = *(const uint4*)(Ap + k0 + 24);
        uint4 bv = *(const uint4*)(Bp + (size_t)bn * 1024 + k0 + bq * 8);
        __syncthreads();
        *(uint4*)&As[t * 40 + 0]  = a0;
        *(uint4*)&As[t * 40 + 8]  = a1;
        *(uint4*)&As[t * 40 + 16] = a2;
        *(uint4*)&As[t * 40 + 24] = a3;
        *(uint4*)&Bs[bn * 40 + bq * 8] = bv;
        __syncthreads();
        short8 af[4], bfv[4];
        #pragma unroll
        for (int i = 0; i < 4; ++i)
            af[i] = *(const short8*)&As[(wave * 64 + i * 16 + l15) * 40 + quad * 8];
        #pragma unroll
        for (int j = 0; j < 4; ++j)
            bfv[j] = *(const short8*)&Bs[(j * 16 + l15) * 40 + quad * 8];
        #pragma unroll
        for (int i = 0; i < 4; ++i)
            #pragma unroll
            for (int j = 0; j < 4; ++j)
                acc[i * 4 + j] = __builtin_amdgcn_mfma_f32_16x16x32_bf16(
                    af[i], bfv[j], acc[i * 4 + j], 0, 0, 0);
    }
    #pragma unroll
    for (int i = 0; i < 4; ++i) {
        const int mbase = wave * 64 + i * 16 + quad * 4;
        #pragma unroll
        for (int j = 0; j < 4; ++j) {
            const int nl = j * 16 + l15;
            ushort4 pk;
            pk.x = f2bf(fmaxf(acc[i * 4 + j][0] + b0s[mbase + 0], 0.f));
            pk.y = f2bf(fmaxf(acc[i * 4 + j][1] + b0s[mbase + 1], 0.f));
            pk.z = f2bf(fmaxf(acc[i * 4 + j][2] + b0s[mbase + 2], 0.f));
            pk.w = f2bf(fmaxf(acc[i * 4 + j][3] + b0s[mbase + 3], 0.f));
            *(ushort4*)&H[nl * 264 + mbase] = pk;
        }
    }

    floatx4 acc2[8];
    #pragma unroll
    for (int i = 0; i < 8; ++i) acc2[i] = (floatx4){0.f, 0.f, 0.f, 0.f};
    const int am2 = t & 127, ah = t >> 7;

    for (int kt = 0; kt < 8; ++kt) {
        const int k0 = kt << 5;
        uint4 a0 = *(const uint4*)(Wb3 + (size_t)am2 * 256 + k0 + ah * 16);
        uint4 a1 = *(const uint4*)(Wb3 + (size_t)am2 * 256 + k0 + ah * 16 + 8);
        __syncthreads();
        *(uint4*)&As[am2 * 40 + ah * 16]     = a0;
        *(uint4*)&As[am2 * 40 + ah * 16 + 8] = a1;
        __syncthreads();
        short8 af2[2], bf2[4];
        #pragma unroll
        for (int i = 0; i < 2; ++i)
            af2[i] = *(const short8*)&As[(wave * 32 + i * 16 + l15) * 40 + quad * 8];
        #pragma unroll
        for (int j = 0; j < 4; ++j)
            bf2[j] = *(const short8*)&H[(j * 16 + l15) * 264 + k0 + quad * 8];
        #pragma unroll
        for (int i = 0; i < 2; ++i)
            #pragma unroll
            for (int j = 0; j < 4; ++j)
                acc2[i * 4 + j] = __builtin_amdgcn_mfma_f32_16x16x32_bf16(
                    af2[i], bf2[j], acc2[i * 4 + j], 0, 0, 0);
    }
    #pragma unroll
    for (int i = 0; i < 2; ++i) {
        const int m2 = wave * 32 + i * 16 + quad * 4;
        #pragma unroll
        for (int j = 0; j < 4; ++j) {
            const int n = n0 + j * 16 + l15;
            float* o = outp + ((size_t)b * 128 + m2) * NPTS + n;
            o[0 * NPTS] = fmaxf(acc2[i * 4 + j][0] + b1s[m2 + 0], 0.f);
            o[1 * NPTS] = fmaxf(acc2[i * 4 + j][1] + b1s[m2 + 1], 0.f);
            o[2 * NPTS] = fmaxf(acc2[i * 4 + j][2] + b1s[m2 + 2], 0.f);
            o[3 * NPTS] = fmaxf(acc2[i * 4 + j][3] + b1s[m2 + 3], 0.f);
        }
    }
}

extern "C" void kernel_launch(void* const* d_in, const int* in_sizes, int n_in,
                              void* d_out, int out_size, void* d_ws, size_t ws_size,
                              hipStream_t stream)
{
    const float* x   = (const float*)d_in[0];
    const float* sW0 = (const float*)d_in[1];
    const float* sb0 = (const float*)d_in[2];
    const float* sW1 = (const float*)d_in[3];
    const float* sb1 = (const float*)d_in[4];
    const float* sW2 = (const float*)d_in[5];
    const float* sb2 = (const float*)d_in[6];
    const float* gW0 = (const float*)d_in[7];
    const float* gb0 = (const float*)d_in[8];
    const float* gW1 = (const float*)d_in[9];
    const float* gb1 = (const float*)d_in[10];
    const float* mW0 = (const float*)d_in[11];
    const float* mb0 = (const float*)d_in[12];
    const float* mW1 = (const float*)d_in[13];
    const float* mb1 = (const float*)d_in[14];
    float* outp = (float*)d_out;

    char* ws = (char*)d_ws;
    int*            idx     = (int*)(ws);                        // 2 MB
    float4*         pts4    = (float4*)(ws + 2097152u);          // 256 KB
    unsigned short* Wb0     = (unsigned short*)(ws + 2359296u);  // 192 KB  gW0 bf16
    unsigned short* Wb1     = (unsigned short*)(ws + 2555904u);  // 512 KB  gW1 bf16
    unsigned short* Wb2     = (unsigned short*)(ws + 3080192u);  // 512 KB  mW0 bf16
    unsigned short* Wb3     = (unsigned short*)(ws + 3604480u);  // 64 KB   mW1 bf16
    unsigned short* Wb4     = (unsigned short*)(ws + 3670016u);  // 24 KB   sW1 bf16
    unsigned short* Wb5     = (unsigned short*)(ws + 3694592u);  // 48 KB   sW2 bf16
    unsigned short* F       = (unsigned short*)(ws + 4194304u);  // 12.6 MB [b][n][384] bf16
    unsigned short* point_t = (unsigned short*)(ws + 18874368u); // 12.6 MB [b][n][384] bf16
    unsigned short* gf0t    = (unsigned short*)(ws + 33554432u); // 8.4 MB  [b][n][256] bf16
    unsigned short* gft     = (unsigned short*)(ws + 50331648u); // 33.6 MB [b][n][1024] bf16

    prep_all<<<dim3(2768), dim3(256), 0, stream>>>(
        x, pts4, gW0, gW1, mW0, mW1, sW1, sW2, Wb0, Wb1, Wb2, Wb3, Wb4, Wb5);
    knn_kernel19<<<dim3(8192), dim3(256), 0, stream>>>(pts4, idx);
    pointmlp_mfma<<<dim3(512, 3), dim3(256), 0, stream>>>(
        x, sW0, sb0, Wb4, sb1, Wb5, sb2, F);
    maxgather_bf16<<<dim3(4096), dim3(192), 0, stream>>>(F, idx, point_t);
    gemm_bf16<0><<<dim3(2, 32, 4), dim3(256), 0, stream>>>(
        Wb0, point_t, gb0, gf0t, nullptr, 256, 384);
    gemm_bf16<1><<<dim3(8, 32, 4), dim3(256), 0, stream>>>(
        Wb1, gf0t, gb1, gft, outp, 1024, 256);
    fused_head<<<dim3(64, 4), dim3(256), 0, stream>>>(
        Wb2, Wb3, mb0, mb1, gft, outp + 4096);
}

// Round 12
// 233.920 us; speedup vs baseline: 1.0373x; 1.0373x over previous
//
#include <hip/hip_runtime.h>
#include <hip/hip_bf16.h>

#define NPTS 4096
#define KNN  32

typedef __attribute__((ext_vector_type(8))) short short8;
typedef __attribute__((ext_vector_type(4))) float floatx4;
typedef unsigned short u16x2 __attribute__((ext_vector_type(2)));

__device__ __forceinline__ unsigned short f2bf(float f) {
    unsigned u = __float_as_uint(f);
    u = (u + 0x7FFFu + ((u >> 16) & 1u)) >> 16;
    return (unsigned short)u;
}

// ---------------- Kernel 0: pack points + convert weights to bf16 ------------
__global__ __launch_bounds__(256) void prep_all(
    const float* __restrict__ x, float4* __restrict__ pts4,
    const float* __restrict__ gW0, const float* __restrict__ gW1,
    const float* __restrict__ mW0, const float* __restrict__ mW1,
    const float* __restrict__ sW1, const float* __restrict__ sW2,
    unsigned short* __restrict__ Wb0, unsigned short* __restrict__ Wb1,
    unsigned short* __restrict__ Wb2, unsigned short* __restrict__ Wb3,
    unsigned short* __restrict__ Wb4, unsigned short* __restrict__ Wb5)
{
    const int blk = blockIdx.x, t = threadIdx.x;
    if (blk < 64) {
        const int i = blk * 256 + t;                 // 0..16383 = b*4096+n
        const int b = i >> 12, n = i & (NPTS - 1);
        const float* xb = x + (size_t)b * 3 * NPTS;
        const float qx = xb[n], qy = xb[NPTS + n], qz = xb[2 * NPTS + n];
        pts4[i] = make_float4(qx, qy, qz, qx * qx + qy * qy + qz * qz);
    } else {
        const int wi = (blk - 64) * 256 + t;         // 0..692223 (exact)
        float v; unsigned short* dst;
        if (wi < 98304)       { v = gW0[wi];          dst = Wb0 + wi; }
        else if (wi < 360448) { v = gW1[wi - 98304];  dst = Wb1 + (wi - 98304); }
        else if (wi < 622592) { v = mW0[wi - 360448]; dst = Wb2 + (wi - 360448); }
        else if (wi < 655360) { v = mW1[wi - 622592]; dst = Wb3 + (wi - 622592); }
        else if (wi < 667648) { v = sW1[wi - 655360]; dst = Wb4 + (wi - 655360); }
        else                  { v = sW2[wi - 667648]; dst = Wb5 + (wi - 667648); }
        *dst = f2bf(v);
    }
}

// ---------------- Kernel 1: FUSED knn19 + low-LDS pointmlp -------------------
// R8's fusion failed because pointmlp's 39 KB LDS union capped the CU at 4
// blocks, running knn (16/19 of blocks) at 33% occupancy. Fix: pointmlp's
// W1/W2 A-fragments are read DIRECTLY from global (L2-resident, per-lane 16 B
// distinct rows — clean dwordx4 pattern), dropping pm LDS to ~11.4 KB. Union
// ~11.5 KB -> 8 blocks/CU (wave-limited, same as standalone knn). Grid
// 512 x 19: per group 3 pm blocks + 16 knn pair-blocks. Both code paths are
// value-identical to the R10-passing kernels; per-block-uniform branch.
__global__ __launch_bounds__(256) void knn_pm_fused(
    const float4* __restrict__ pts4, int* __restrict__ knn_out,
    const float* __restrict__ x,
    const float* __restrict__ sW0, const float* __restrict__ sb0,
    const unsigned short* __restrict__ W1b, const float* __restrict__ sb1,
    const unsigned short* __restrict__ W2b, const float* __restrict__ sb2,
    unsigned short* __restrict__ F)
{
    __shared__ __align__(16) char smem[11776];

    const int t = threadIdx.x;
    const int grp = blockIdx.x / 19, rr = blockIdx.x % 19;

    if (rr < 3) {
        // =================== pointmlp path (pm_id in [0,1536)) ==============
        const int pm_id = grp * 3 + rr;
        unsigned short* h0T = (unsigned short*)(smem);            // 4608 B
        unsigned short* h1T = (unsigned short*)(smem + 4608);     // 4608 B
        float* W0s = (float*)(smem + 9216);                       //  768 B
        float* b0s = (float*)(smem + 9984);                       //  256 B
        float* b1s = (float*)(smem + 10240);                      //  256 B
        float* b2s = (float*)(smem + 10496);                      //  512 B
        float* pts = (float*)(smem + 11008);                      //  396 B

        const int s = pm_id / 512;
        const int tile = pm_id % 512;
        const int b = tile >> 7;
        const int j0 = (tile & 127) << 5;
        const float* xb = x + (size_t)b * 3 * NPTS;

        if (t < 192) W0s[t] = sW0[s * 192 + t];
        if (t < 64) b0s[t] = sb0[s * 64 + t];
        if (t >= 64 && t < 128) b1s[t - 64] = sb1[s * 64 + (t - 64)];
        if (t < 128) b2s[t] = sb2[s * 128 + t];
        if (t < 96) { int c = t >> 5, p = t & 31; pts[c * 33 + p] = xb[c * NPTS + j0 + p]; }
        __syncthreads();

        {   // layer 1 (fp32): h0T[p][og*8..+7]
            const int p = t & 31, og = t >> 5;
            const float xx = pts[p], yy = pts[33 + p], zz = pts[66 + p];
            unsigned short hv[8];
            #pragma unroll
            for (int r = 0; r < 8; ++r) {
                const int o = og * 8 + r;
                float a = b0s[o] + W0s[o * 3] * xx + W0s[o * 3 + 1] * yy
                        + W0s[o * 3 + 2] * zz;
                hv[r] = f2bf(fmaxf(a, 0.0f));
            }
            *(uint4*)&h0T[p * 72 + og * 8] = *(const uint4*)hv;
        }
        __syncthreads();

        const int w = t >> 6, lane = t & 63, quad = lane >> 4, l15 = lane & 15;
        const unsigned short* W1g = W1b + (size_t)s * 4096;   // [64][64]
        const unsigned short* W2g = W2b + (size_t)s * 8192;   // [128][64]

        {   // layer 2: A-frag from GLOBAL W1 (identical bytes to LDS-staged)
            #pragma unroll
            for (int ni = 0; ni < 2; ++ni) {
                floatx4 acc = (floatx4){0.f, 0.f, 0.f, 0.f};
                #pragma unroll
                for (int k0 = 0; k0 < 2; ++k0) {
                    short8 aF = *(const short8*)(W1g + (w * 16 + l15) * 64 +
                                                 k0 * 32 + quad * 8);
                    short8 bF = *(const short8*)&h0T[(ni * 16 + l15) * 72 + k0 * 32 + quad * 8];
                    acc = __builtin_amdgcn_mfma_f32_16x16x32_bf16(aF, bF, acc, 0, 0, 0);
                }
                const int m0 = w * 16 + quad * 4;
                const int p = ni * 16 + l15;
                ushort4 pk;
                pk.x = f2bf(fmaxf(acc[0] + b1s[m0 + 0], 0.f));
                pk.y = f2bf(fmaxf(acc[1] + b1s[m0 + 1], 0.f));
                pk.z = f2bf(fmaxf(acc[2] + b1s[m0 + 2], 0.f));
                pk.w = f2bf(fmaxf(acc[3] + b1s[m0 + 3], 0.f));
                *(ushort4*)&h1T[p * 72 + m0] = pk;
            }
        }
        __syncthreads();

        {   // layer 3: A-frag from GLOBAL W2
            #pragma unroll
            for (int mi = 0; mi < 2; ++mi) {
                const int m0 = (w * 2 + mi) * 16;
                #pragma unroll
                for (int ni = 0; ni < 2; ++ni) {
                    floatx4 acc = (floatx4){0.f, 0.f, 0.f, 0.f};
                    #pragma unroll
                    for (int k0 = 0; k0 < 2; ++k0) {
                        short8 aF = *(const short8*)(W2g + (m0 + l15) * 64 +
                                                     k0 * 32 + quad * 8);
                        short8 bF = *(const short8*)&h1T[(ni * 16 + l15) * 72 + k0 * 32 + quad * 8];
                        acc = __builtin_amdgcn_mfma_f32_16x16x32_bf16(aF, bF, acc, 0, 0, 0);
                    }
                    const int o2 = m0 + quad * 4;
                    const int j = j0 + ni * 16 + l15;
                    ushort4 pk;
                    pk.x = f2bf(fmaxf(acc[0] + b2s[o2 + 0], 0.f));
                    pk.y = f2bf(fmaxf(acc[1] + b2s[o2 + 1], 0.f));
                    pk.z = f2bf(fmaxf(acc[2] + b2s[o2 + 2], 0.f));
                    pk.w = f2bf(fmaxf(acc[3] + b2s[o2 + 3], 0.f));
                    *(ushort4*)&F[((size_t)b * NPTS + j) * 384 + s * 128 + o2] = pk;
                }
            }
        }
        return;
    }

    // ======================= knn path (pairs, verbatim knn19) ===============
    unsigned (*sredA)[4]   = (unsigned(*)[4])(smem);              //   32 B
    unsigned (*sredB)[4]   = (unsigned(*)[4])(smem + 32);         //   32 B
    unsigned* minSA        = (unsigned*)(smem + 64);              // 1024 B
    unsigned* minSB        = (unsigned*)(smem + 1088);            // 1024 B
    unsigned long long* CA = (unsigned long long*)(smem + 2112);  // 2048 B
    unsigned long long* CB = (unsigned long long*)(smem + 4160);  // 2048 B
    unsigned* ccnt2        = (unsigned*)(smem + 6208);            //    8 B

    const int wid = t >> 6, lane = t & 63;
    const int pr = grp * 16 + (rr - 3);      // 0..8191 = b*2048 + pair
    const int b  = pr >> 11;
    const int qa = ((pr & 2047) << 1);
    const int qb = qa + 1;
    const float4* P = pts4 + ((size_t)b << 12);
    const float4 sA = P[qa];
    const float4 sB = P[qb];

    if (t < 2) ccnt2[t] = 0u;
    CA[t] = 0xFFFFFFFFFFFFFFFFULL;           // pad for fixed-64 rank (B1 orders)
    CB[t] = 0xFFFFFFFFFFFFFFFFULL;

    unsigned kA[16], kB[16];
    #pragma unroll
    for (int g = 0; g < 4; ++g) {
        float4 c0 = P[((g * 4 + 0) << 8) + t];
        float4 c1 = P[((g * 4 + 1) << 8) + t];
        float4 c2 = P[((g * 4 + 2) << 8) + t];
        float4 c3 = P[((g * 4 + 3) << 8) + t];
        float dA0 = (sA.w + c0.w) - 2.0f * (sA.x * c0.x + sA.y * c0.y + sA.z * c0.z);
        float dA1 = (sA.w + c1.w) - 2.0f * (sA.x * c1.x + sA.y * c1.y + sA.z * c1.z);
        float dA2 = (sA.w + c2.w) - 2.0f * (sA.x * c2.x + sA.y * c2.y + sA.z * c2.z);
        float dA3 = (sA.w + c3.w) - 2.0f * (sA.x * c3.x + sA.y * c3.y + sA.z * c3.z);
        float dB0 = (sB.w + c0.w) - 2.0f * (sB.x * c0.x + sB.y * c0.y + sB.z * c0.z);
        float dB1 = (sB.w + c1.w) - 2.0f * (sB.x * c1.x + sB.y * c1.y + sB.z * c1.z);
        float dB2 = (sB.w + c2.w) - 2.0f * (sB.x * c2.x + sB.y * c2.y + sB.z * c2.z);
        float dB3 = (sB.w + c3.w) - 2.0f * (sB.x * c3.x + sB.y * c3.y + sB.z * c3.z);
        unsigned uA0 = __float_as_uint(dA0), uA1 = __float_as_uint(dA1);
        unsigned uA2 = __float_as_uint(dA2), uA3 = __float_as_uint(dA3);
        unsigned uB0 = __float_as_uint(dB0), uB1 = __float_as_uint(dB1);
        unsigned uB2 = __float_as_uint(dB2), uB3 = __float_as_uint(dB3);
        kA[g * 4 + 0] = uA0 ^ (((unsigned)((int)uA0 >> 31)) | 0x80000000u);
        kA[g * 4 + 1] = uA1 ^ (((unsigned)((int)uA1 >> 31)) | 0x80000000u);
        kA[g * 4 + 2] = uA2 ^ (((unsigned)((int)uA2 >> 31)) | 0x80000000u);
        kA[g * 4 + 3] = uA3 ^ (((unsigned)((int)uA3 >> 31)) | 0x80000000u);
        kB[g * 4 + 0] = uB0 ^ (((unsigned)((int)uB0 >> 31)) | 0x80000000u);
        kB[g * 4 + 1] = uB1 ^ (((unsigned)((int)uB1 >> 31)) | 0x80000000u);
        kB[g * 4 + 2] = uB2 ^ (((unsigned)((int)uB2 >> 31)) | 0x80000000u);
        kB[g * 4 + 3] = uB3 ^ (((unsigned)((int)uB3 >> 31)) | 0x80000000u);
    }

    unsigned tmA = kA[0], tmB = kB[0];
    #pragma unroll
    for (int r = 1; r < 16; ++r) {
        tmA = (kA[r] < tmA) ? kA[r] : tmA;
        tmB = (kB[r] < tmB) ? kB[r] : tmB;
    }
    minSA[t] = tmA;
    minSB[t] = tmB;
    __syncthreads();                                   // B1

    unsigned mA = minSA[lane], mB = minSB[lane];
    {
        unsigned a1 = minSA[lane + 64], a2 = minSA[lane + 128], a3 = minSA[lane + 192];
        unsigned b1 = minSB[lane + 64], b2 = minSB[lane + 128], b3 = minSB[lane + 192];
        mA = (a1 < mA) ? a1 : mA;  a2 = (a3 < a2) ? a3 : a2;  mA = (a2 < mA) ? a2 : mA;
        mB = (b1 < mB) ? b1 : mB;  b2 = (b3 < b2) ? b3 : b2;  mB = (b2 < mB) ? b2 : mB;
    }

    const unsigned msA = mA >> 16, msB = mB >> 16;
    unsigned loA = 0u, hiA = 0xFFFFu, loB = 0u, hiB = 0xFFFFu;
    for (int i = 0; i < 16; ++i) {
        const unsigned midA = (loA + hiA) >> 1;
        const unsigned midB = (loB + hiB) >> 1;
        const unsigned cA = (unsigned)__popcll(__ballot(msA <= midA));
        const unsigned cB = (unsigned)__popcll(__ballot(msB <= midB));
        if (cA >= 33u) hiA = midA; else loA = midA + 1u;
        if (cB >= 33u) hiB = midB; else loB = midB + 1u;
    }
    const unsigned thrA = (hiA << 16) | 0xFFFFu;
    const unsigned thrB = (hiB << 16) | 0xFFFFu;

    #pragma unroll
    for (int r = 0; r < 16; ++r) {
        if (kA[r] <= thrA) {
            unsigned p = atomicAdd(&ccnt2[0], 1u);
            if (p < 256u)
                CA[p] = ((unsigned long long)kA[r] << 32) | (unsigned)((r << 8) + t);
        }
        if (kB[r] <= thrB) {
            unsigned p = atomicAdd(&ccnt2[1], 1u);
            if (p < 256u)
                CB[p] = ((unsigned long long)kB[r] << 32) | (unsigned)((r << 8) + t);
        }
    }
    __syncthreads();                                   // B2

    int ncA = (int)ccnt2[0];
    int ncB = (int)ccnt2[1];
    bool fell_back = false;
    if (ncA > 256 || ncB > 256) {
        fell_back = true;
        if (t < 2) ccnt2[t] = 0u;
        int pp = 0;
        auto countLE2 = [&](unsigned ta, unsigned tb, unsigned& ga, unsigned& gb) {
            unsigned ca = 0, cb = 0;
            #pragma unroll
            for (int r = 0; r < 16; ++r) {
                ca += (unsigned)__popcll(__ballot(kA[r] <= ta));
                cb += (unsigned)__popcll(__ballot(kB[r] <= tb));
            }
            if (lane == 0) { sredA[pp & 1][wid] = ca; sredB[pp & 1][wid] = cb; }
            __syncthreads();
            ga = sredA[pp & 1][0] + sredA[pp & 1][1] +
                 sredA[pp & 1][2] + sredA[pp & 1][3];
            gb = sredB[pp & 1][0] + sredB[pp & 1][1] +
                 sredB[pp & 1][2] + sredB[pp & 1][3];
            ++pp;
        };
        unsigned lo2A = 0x100u, hi2A = 0x1FEu, cHiA = 4096u;
        unsigned lo2B = 0x100u, hi2B = 0x1FEu, cHiB = 4096u;
        for (int it = 0; it < 8; ++it) {
            const unsigned mAe = (lo2A + hi2A) >> 1;
            const unsigned mBe = (lo2B + hi2B) >> 1;
            unsigned ga, gb;
            countLE2((mAe << 23) | 0x7FFFFFu, (mBe << 23) | 0x7FFFFFu, ga, gb);
            if (ga >= 33u) { hi2A = mAe; cHiA = ga; } else lo2A = mAe + 1u;
            if (gb >= 33u) { hi2B = mBe; cHiB = gb; } else lo2B = mBe + 1u;
        }
        unsigned loKA = lo2A << 23, hiKA = (lo2A << 23) | 0x7FFFFFu, cFA = cHiA;
        unsigned loKB = lo2B << 23, hiKB = (lo2B << 23) | 0x7FFFFFu, cFB = cHiB;
        while (((cFA > 256u) && (loKA < hiKA)) || ((cFB > 256u) && (loKB < hiKB))) {
            const bool nAx = (cFA > 256u) && (loKA < hiKA);
            const bool nBx = (cFB > 256u) && (loKB < hiKB);
            const unsigned mAk = nAx ? (loKA + ((hiKA - loKA) >> 1)) : hiKA;
            const unsigned mBk = nBx ? (loKB + ((hiKB - loKB) >> 1)) : hiKB;
            unsigned ga, gb;
            countLE2(mAk, mBk, ga, gb);
            if (nAx) { if (ga >= 33u) { hiKA = mAk; cFA = ga; } else loKA = mAk + 1u; }
            if (nBx) { if (gb >= 33u) { hiKB = mBk; cFB = gb; } else loKB = mBk + 1u; }
        }
        const unsigned tFA = hiKA, tFB = hiKB;
        #pragma unroll
        for (int r = 0; r < 16; ++r) {
            if (kA[r] <= tFA) {
                unsigned p = atomicAdd(&ccnt2[0], 1u);
                if (p < 256u)
                    CA[p] = ((unsigned long long)kA[r] << 32) | (unsigned)((r << 8) + t);
            }
            if (kB[r] <= tFB) {
                unsigned p = atomicAdd(&ccnt2[1], 1u);
                if (p < 256u)
                    CB[p] = ((unsigned long long)kB[r] << 32) | (unsigned)((r << 8) + t);
            }
        }
        __syncthreads();
        ncA = (int)ccnt2[0]; if (ncA > 256) ncA = 256;
        ncB = (int)ccnt2[1]; if (ncB > 256) ncB = 256;
    }

    if (!fell_back && ncA <= 64 && ncB <= 64) {
        if (t < 64) {
            const unsigned long long me = CA[t];
            int rank = 0;
            #pragma unroll
            for (int j = 0; j < 64; ++j) rank += (CA[j] < me) ? 1 : 0;
            if (rank >= 1 && rank <= KNN)
                knn_out[((size_t)((b << 12) + qa)) * KNN + (rank - 1)] =
                    (int)(me & 0xFFFFFFFFu);
        } else if (t < 128) {
            const int tb = t - 64;
            const unsigned long long me = CB[tb];
            int rank = 0;
            #pragma unroll
            for (int j = 0; j < 64; ++j) rank += (CB[j] < me) ? 1 : 0;
            if (rank >= 1 && rank <= KNN)
                knn_out[((size_t)((b << 12) + qb)) * KNN + (rank - 1)] =
                    (int)(me & 0xFFFFFFFFu);
        }
    } else {
        if (t < ncA) {
            const unsigned long long me = CA[t];
            int rank = 0;
            for (int j = 0; j < ncA; ++j) rank += (CA[j] < me) ? 1 : 0;
            if (rank >= 1 && rank <= KNN)
                knn_out[((size_t)((b << 12) + qa)) * KNN + (rank - 1)] =
                    (int)(me & 0xFFFFFFFFu);
        }
        if (t < ncB) {
            const unsigned long long me = CB[t];
            int rank = 0;
            for (int j = 0; j < ncB; ++j) rank += (CB[j] < me) ? 1 : 0;
            if (rank >= 1 && rank <= KNN)
                knn_out[((size_t)((b << 12) + qb)) * KNN + (rank - 1)] =
                    (int)(me & 0xFFFFFFFFu);
        }
    }
}

// ---------------- Kernel 3: gather-max, 2 channels/lane (R10-passing) --------
__global__ __launch_bounds__(192) void maxgather_bf16(
    const unsigned short* __restrict__ F, const int* __restrict__ knn,
    unsigned short* __restrict__ pt)
{
    __shared__ int idxS[KNN];
    const int q = blockIdx.x;            // b*4096 + n
    const int b = q >> 12;
    const int t = threadIdx.x;           // channel-pair 0..191
    if (t < KNN) idxS[t] = knn[(size_t)q * KNN + t];
    __syncthreads();
    const unsigned short* Fb = F + (size_t)b * NPTS * 384 + t * 2;
    u16x2 m = (u16x2)0;
    #pragma unroll 8
    for (int k = 0; k < KNN; ++k) {
        u16x2 v = *(const u16x2*)(Fb + (size_t)idxS[k] * 384);
        m = __builtin_elementwise_max(m, v);
    }
    *(u16x2*)(pt + (size_t)q * 384 + t * 2) = m;
}

// ---------------- Kernel 4: bf16 MFMA GEMM + bias + relu (R10-passing) -------
template<int DO_ROWMAX>
__global__ __launch_bounds__(256) void gemm_bf16(
    const unsigned short* __restrict__ Wb, const unsigned short* __restrict__ Bt,
    const float* __restrict__ bias, void* __restrict__ outp,
    float* __restrict__ gfeat, int M, int K)
{
    __shared__ __align__(16) unsigned short As[128 * 40];
    __shared__ __align__(16) unsigned short Bs[128 * 40];
    __shared__ float biasS[128];
    __shared__ int redI[128];

    const int t = threadIdx.x;
    const int b = blockIdx.z;
    const int m0 = blockIdx.x * 128;
    const int n0 = blockIdx.y * 128;
    if (t < 128) biasS[t] = bias[m0 + t];
    if (DO_ROWMAX && t < 128) redI[t] = 0;

    const int wave = t >> 6, lane = t & 63, quad = lane >> 4, l15 = lane & 15;
    const int wr = wave >> 1, wc = wave & 1;

    const int am = t & 127, akh = t >> 7;
    const unsigned short* Wp = Wb + (size_t)(m0 + am) * K + akh * 16;
    const int bn = t >> 2, bq = t & 3;
    const unsigned short* Bp = Bt + ((size_t)b * NPTS + n0) * K;

    floatx4 acc[16];
    #pragma unroll
    for (int i = 0; i < 16; ++i) acc[i] = (floatx4){0.f, 0.f, 0.f, 0.f};

    const int nk = K >> 5;
    for (int kt = 0; kt < nk; ++kt) {
        const int k0 = kt << 5;
        uint4 av0 = *(const uint4*)(Wp + k0);
        uint4 av1 = *(const uint4*)(Wp + k0 + 8);
        uint4 bv0 = *(const uint4*)(Bp + (size_t)bn * K + k0 + bq * 8);
        uint4 bv1 = *(const uint4*)(Bp + (size_t)(bn + 64) * K + k0 + bq * 8);
        __syncthreads();
        {
            uint4* dst = (uint4*)&As[am * 40 + akh * 16];
            dst[0] = av0;
            dst[1] = av1;
            *(uint4*)&Bs[bn * 40 + bq * 8] = bv0;
            *(uint4*)&Bs[(bn + 64) * 40 + bq * 8] = bv1;
        }
        __syncthreads();
        short8 af[4], bfv[4];
        #pragma unroll
        for (int i = 0; i < 4; ++i)
            af[i] = *(const short8*)&As[(wr * 64 + i * 16 + l15) * 40 + quad * 8];
        #pragma unroll
        for (int j = 0; j < 4; ++j)
            bfv[j] = *(const short8*)&Bs[(wc * 64 + j * 16 + l15) * 40 + quad * 8];
        #pragma unroll
        for (int i = 0; i < 4; ++i)
            #pragma unroll
            for (int j = 0; j < 4; ++j)
                acc[i * 4 + j] = __builtin_amdgcn_mfma_f32_16x16x32_bf16(
                    af[i], bfv[j], acc[i * 4 + j], 0, 0, 0);
    }

    #pragma unroll
    for (int i = 0; i < 4; ++i) {
        const int mbase = wr * 64 + i * 16 + quad * 4;
        float rm0 = 0.f, rm1 = 0.f, rm2 = 0.f, rm3 = 0.f;
        #pragma unroll
        for (int j = 0; j < 4; ++j) {
            const int n = n0 + wc * 64 + j * 16 + l15;
            float v0 = fmaxf(acc[i * 4 + j][0] + biasS[mbase + 0], 0.f);
            float v1 = fmaxf(acc[i * 4 + j][1] + biasS[mbase + 1], 0.f);
            float v2 = fmaxf(acc[i * 4 + j][2] + biasS[mbase + 2], 0.f);
            float v3 = fmaxf(acc[i * 4 + j][3] + biasS[mbase + 3], 0.f);
            if (DO_ROWMAX) {
                rm0 = fmaxf(rm0, v0); rm1 = fmaxf(rm1, v1);
                rm2 = fmaxf(rm2, v2); rm3 = fmaxf(rm3, v3);
            }
            ushort4 pk;
            pk.x = f2bf(v0); pk.y = f2bf(v1); pk.z = f2bf(v2); pk.w = f2bf(v3);
            *(ushort4*)((unsigned short*)outp +
                        ((size_t)b * NPTS + n) * M + m0 + mbase) = pk;
        }
        if (DO_ROWMAX) {
            atomicMax(&redI[mbase + 0], __float_as_int(rm0));
            atomicMax(&redI[mbase + 1], __float_as_int(rm1));
            atomicMax(&redI[mbase + 2], __float_as_int(rm2));
            atomicMax(&redI[mbase + 3], __float_as_int(rm3));
        }
    }
    if (DO_ROWMAX) {
        __syncthreads();
        if (t < 128)
            atomicMax((int*)&gfeat[(size_t)b * 1024 + m0 + t], redI[t]);
    }
}

// ---------------- Kernel 5: fused head = gemm3 + gemm4 (R4-passing, n=64) ----
__global__ __launch_bounds__(256) void fused_head(
    const unsigned short* __restrict__ Wb2, const unsigned short* __restrict__ Wb3,
    const float* __restrict__ mb0, const float* __restrict__ mb1,
    const unsigned short* __restrict__ gft, float* __restrict__ outp)
{
    __shared__ __align__(16) unsigned short As[256 * 40];
    __shared__ __align__(16) unsigned short Bs[64 * 40];
    __shared__ __align__(16) unsigned short H[64 * 264];
    __shared__ float b0s[256];
    __shared__ float b1s[128];

    const int t = threadIdx.x;
    const int n0 = blockIdx.x * 64;
    const int b = blockIdx.y;
    b0s[t] = mb0[t];
    if (t < 128) b1s[t] = mb1[t];

    const int wave = t >> 6, lane = t & 63, quad = lane >> 4, l15 = lane & 15;

    const unsigned short* Ap = Wb2 + (size_t)t * 1024;
    const int bn = t >> 2, bq = t & 3;
    const unsigned short* Bp = gft + ((size_t)b * NPTS + n0) * 1024;

    floatx4 acc[16];
    #pragma unroll
    for (int i = 0; i < 16; ++i) acc[i] = (floatx4){0.f, 0.f, 0.f, 0.f};

    for (int kt = 0; kt < 32; ++kt) {
        const int k0 = kt << 5;
        uint4 a0 = *(const uint4*)(Ap + k0);
        uint4 a1 = *(const uint4*)(Ap + k0 + 8);
        uint4 a2 = *(const uint4*)(Ap + k0 + 16);
        uint4 a3 = *(const uint4*)(Ap + k0 + 24);
        uint4 bv = *(const uint4*)(Bp + (size_t)bn * 1024 + k0 + bq * 8);
        __syncthreads();
        *(uint4*)&As[t * 40 + 0]  = a0;
        *(uint4*)&As[t * 40 + 8]  = a1;
        *(uint4*)&As[t * 40 + 16] = a2;
        *(uint4*)&As[t * 40 + 24] = a3;
        *(uint4*)&Bs[bn * 40 + bq * 8] = bv;
        __syncthreads();
        short8 af[4], bfv[4];
        #pragma unroll
        for (int i = 0; i < 4; ++i)
            af[i] = *(const short8*)&As[(wave * 64 + i * 16 + l15) * 40 + quad * 8];
        #pragma unroll
        for (int j = 0; j < 4; ++j)
            bfv[j] = *(const short8*)&Bs[(j * 16 + l15) * 40 + quad * 8];
        #pragma unroll
        for (int i = 0; i < 4; ++i)
            #pragma unroll
            for (int j = 0; j < 4; ++j)
                acc[i * 4 + j] = __builtin_amdgcn_mfma_f32_16x16x32_bf16(
                    af[i], bfv[j], acc[i * 4 + j], 0, 0, 0);
    }
    #pragma unroll
    for (int i = 0; i < 4; ++i) {
        const int mbase = wave * 64 + i * 16 + quad * 4;
        #pragma unroll
        for (int j = 0; j < 4; ++j) {
            const int nl = j * 16 + l15;
            ushort4 pk;
            pk.x = f2bf(fmaxf(acc[i * 4 + j][0] + b0s[mbase + 0], 0.f));
            pk.y = f2bf(fmaxf(acc[i * 4 + j][1] + b0s[mbase + 1], 0.f));
            pk.z = f2bf(fmaxf(acc[i * 4 + j][2] + b0s[mbase + 2], 0.f));
            pk.w = f2bf(fmaxf(acc[i * 4 + j][3] + b0s[mbase + 3], 0.f));
            *(ushort4*)&H[nl * 264 + mbase] = pk;
        }
    }

    floatx4 acc2[8];
    #pragma unroll
    for (int i = 0; i < 8; ++i) acc2[i] = (floatx4){0.f, 0.f, 0.f, 0.f};
    const int am2 = t & 127, ah = t >> 7;

    for (int kt = 0; kt < 8; ++kt) {
        const int k0 = kt << 5;
        uint4 a0 = *(const uint4*)(Wb3 + (size_t)am2 * 256 + k0 + ah * 16);
        uint4 a1 = *(const uint4*)(Wb3 + (size_t)am2 * 256 + k0 + ah * 16 + 8);
        __syncthreads();
        *(uint4*)&As[am2 * 40 + ah * 16]     = a0;
        *(uint4*)&As[am2 * 40 + ah * 16 + 8] = a1;
        __syncthreads();
        short8 af2[2], bf2[4];
        #pragma unroll
        for (int i = 0; i < 2; ++i)
            af2[i] = *(const short8*)&As[(wave * 32 + i * 16 + l15) * 40 + quad * 8];
        #pragma unroll
        for (int j = 0; j < 4; ++j)
            bf2[j] = *(const short8*)&H[(j * 16 + l15) * 264 + k0 + quad * 8];
        #pragma unroll
        for (int i = 0; i < 2; ++i)
            #pragma unroll
            for (int j = 0; j < 4; ++j)
                acc2[i * 4 + j] = __builtin_amdgcn_mfma_f32_16x16x32_bf16(
                    af2[i], bf2[j], acc2[i * 4 + j], 0, 0, 0);
    }
    #pragma unroll
    for (int i = 0; i < 2; ++i) {
        const int m2 = wave * 32 + i * 16 + quad * 4;
        #pragma unroll
        for (int j = 0; j < 4; ++j) {
            const int n = n0 + j * 16 + l15;
            float* o = outp + ((size_t)b * 128 + m2) * NPTS + n;
            o[0 * NPTS] = fmaxf(acc2[i * 4 + j][0] + b1s[m2 + 0], 0.f);
            o[1 * NPTS] = fmaxf(acc2[i * 4 + j][1] + b1s[m2 + 1], 0.f);
            o[2 * NPTS] = fmaxf(acc2[i * 4 + j][2] + b1s[m2 + 2], 0.f);
            o[3 * NPTS] = fmaxf(acc2[i * 4 + j][3] + b1s[m2 + 3], 0.f);
        }
    }
}

extern "C" void kernel_launch(void* const* d_in, const int* in_sizes, int n_in,
                              void* d_out, int out_size, void* d_ws, size_t ws_size,
                              hipStream_t stream)
{
    const float* x   = (const float*)d_in[0];
    const float* sW0 = (const float*)d_in[1];
    const float* sb0 = (const float*)d_in[2];
    const float* sW1 = (const float*)d_in[3];
    const float* sb1 = (const float*)d_in[4];
    const float* sW2 = (const float*)d_in[5];
    const float* sb2 = (const float*)d_in[6];
    const float* gW0 = (const float*)d_in[7];
    const float* gb0 = (const float*)d_in[8];
    const float* gW1 = (const float*)d_in[9];
    const float* gb1 = (const float*)d_in[10];
    const float* mW0 = (const float*)d_in[11];
    const float* mb0 = (const float*)d_in[12];
    const float* mW1 = (const float*)d_in[13];
    const float* mb1 = (const float*)d_in[14];
    float* outp = (float*)d_out;

    char* ws = (char*)d_ws;
    int*            idx     = (int*)(ws);                        // 2 MB
    float4*         pts4    = (float4*)(ws + 2097152u);          // 256 KB
    unsigned short* Wb0     = (unsigned short*)(ws + 2359296u);  // 192 KB  gW0 bf16
    unsigned short* Wb1     = (unsigned short*)(ws + 2555904u);  // 512 KB  gW1 bf16
    unsigned short* Wb2     = (unsigned short*)(ws + 3080192u);  // 512 KB  mW0 bf16
    unsigned short* Wb3     = (unsigned short*)(ws + 3604480u);  // 64 KB   mW1 bf16
    unsigned short* Wb4     = (unsigned short*)(ws + 3670016u);  // 24 KB   sW1 bf16
    unsigned short* Wb5     = (unsigned short*)(ws + 3694592u);  // 48 KB   sW2 bf16
    unsigned short* F       = (unsigned short*)(ws + 4194304u);  // 12.6 MB [b][n][384] bf16
    unsigned short* point_t = (unsigned short*)(ws + 18874368u); // 12.6 MB [b][n][384] bf16
    unsigned short* gf0t    = (unsigned short*)(ws + 33554432u); // 8.4 MB  [b][n][256] bf16
    unsigned short* gft     = (unsigned short*)(ws + 50331648u); // 33.6 MB [b][n][1024] bf16

    prep_all<<<dim3(2768), dim3(256), 0, stream>>>(
        x, pts4, gW0, gW1, mW0, mW1, sW1, sW2, Wb0, Wb1, Wb2, Wb3, Wb4, Wb5);
    knn_pm_fused<<<dim3(9728), dim3(256), 0, stream>>>(
        pts4, idx, x, sW0, sb0, Wb4, sb1, Wb5, sb2, F);
    maxgather_bf16<<<dim3(16384), dim3(192), 0, stream>>>(F, idx, point_t);
    gemm_bf16<0><<<dim3(2, 32, 4), dim3(256), 0, stream>>>(
        Wb0, point_t, gb0, gf0t, nullptr, 256, 384);
    gemm_bf16<1><<<dim3(8, 32, 4), dim3(256), 0, stream>>>(
        Wb1, gf0t, gb1, gft, outp, 1024, 256);
    fused_head<<<dim3(64, 4), dim3(256), 0, stream>>>(
        Wb2, Wb3, mb0, mb1, gft, outp + 4096);
}

// Round 13
// 232.917 us; speedup vs baseline: 1.0418x; 1.0043x over previous
//
#include <hip/hip_runtime.h>
#include <hip/hip_bf16.h>

#define NPTS 4096
#define KNN  32

typedef __attribute__((ext_vector_type(8))) short short8;
typedef __attribute__((ext_vector_type(4))) float floatx4;
typedef unsigned short u16x2 __attribute__((ext_vector_type(2)));

__device__ __forceinline__ unsigned short f2bf(float f) {
    unsigned u = __float_as_uint(f);
    u = (u + 0x7FFFu + ((u >> 16) & 1u)) >> 16;
    return (unsigned short)u;
}

// ---------------- Kernel 0: pack points + convert weights to bf16 ------------
__global__ __launch_bounds__(256) void prep_all(
    const float* __restrict__ x, float4* __restrict__ pts4,
    const float* __restrict__ gW0, const float* __restrict__ gW1,
    const float* __restrict__ mW0, const float* __restrict__ mW1,
    const float* __restrict__ sW1, const float* __restrict__ sW2,
    unsigned short* __restrict__ Wb0, unsigned short* __restrict__ Wb1,
    unsigned short* __restrict__ Wb2, unsigned short* __restrict__ Wb3,
    unsigned short* __restrict__ Wb4, unsigned short* __restrict__ Wb5)
{
    const int blk = blockIdx.x, t = threadIdx.x;
    if (blk < 64) {
        const int i = blk * 256 + t;                 // 0..16383 = b*4096+n
        const int b = i >> 12, n = i & (NPTS - 1);
        const float* xb = x + (size_t)b * 3 * NPTS;
        const float qx = xb[n], qy = xb[NPTS + n], qz = xb[2 * NPTS + n];
        pts4[i] = make_float4(qx, qy, qz, qx * qx + qy * qy + qz * qz);
    } else {
        const int wi = (blk - 64) * 256 + t;         // 0..692223 (exact)
        float v; unsigned short* dst;
        if (wi < 98304)       { v = gW0[wi];          dst = Wb0 + wi; }
        else if (wi < 360448) { v = gW1[wi - 98304];  dst = Wb1 + (wi - 98304); }
        else if (wi < 622592) { v = mW0[wi - 360448]; dst = Wb2 + (wi - 360448); }
        else if (wi < 655360) { v = mW1[wi - 622592]; dst = Wb3 + (wi - 622592); }
        else if (wi < 667648) { v = sW1[wi - 655360]; dst = Wb4 + (wi - 655360); }
        else                  { v = sW2[wi - 667648]; dst = Wb5 + (wi - 667648); }
        *dst = f2bf(v);
    }
}

// ---------------- Kernel 1: FUSED knn19 + low-LDS pointmlp (R12-passing) -----
__global__ __launch_bounds__(256) void knn_pm_fused(
    const float4* __restrict__ pts4, int* __restrict__ knn_out,
    const float* __restrict__ x,
    const float* __restrict__ sW0, const float* __restrict__ sb0,
    const unsigned short* __restrict__ W1b, const float* __restrict__ sb1,
    const unsigned short* __restrict__ W2b, const float* __restrict__ sb2,
    unsigned short* __restrict__ F)
{
    __shared__ __align__(16) char smem[11776];

    const int t = threadIdx.x;
    const int grp = blockIdx.x / 19, rr = blockIdx.x % 19;

    if (rr < 3) {
        // =================== pointmlp path (pm_id in [0,1536)) ==============
        const int pm_id = grp * 3 + rr;
        unsigned short* h0T = (unsigned short*)(smem);            // 4608 B
        unsigned short* h1T = (unsigned short*)(smem + 4608);     // 4608 B
        float* W0s = (float*)(smem + 9216);                       //  768 B
        float* b0s = (float*)(smem + 9984);                       //  256 B
        float* b1s = (float*)(smem + 10240);                      //  256 B
        float* b2s = (float*)(smem + 10496);                      //  512 B
        float* pts = (float*)(smem + 11008);                      //  396 B

        const int s = pm_id / 512;
        const int tile = pm_id % 512;
        const int b = tile >> 7;
        const int j0 = (tile & 127) << 5;
        const float* xb = x + (size_t)b * 3 * NPTS;

        if (t < 192) W0s[t] = sW0[s * 192 + t];
        if (t < 64) b0s[t] = sb0[s * 64 + t];
        if (t >= 64 && t < 128) b1s[t - 64] = sb1[s * 64 + (t - 64)];
        if (t < 128) b2s[t] = sb2[s * 128 + t];
        if (t < 96) { int c = t >> 5, p = t & 31; pts[c * 33 + p] = xb[c * NPTS + j0 + p]; }
        __syncthreads();

        {   // layer 1 (fp32): h0T[p][og*8..+7]
            const int p = t & 31, og = t >> 5;
            const float xx = pts[p], yy = pts[33 + p], zz = pts[66 + p];
            unsigned short hv[8];
            #pragma unroll
            for (int r = 0; r < 8; ++r) {
                const int o = og * 8 + r;
                float a = b0s[o] + W0s[o * 3] * xx + W0s[o * 3 + 1] * yy
                        + W0s[o * 3 + 2] * zz;
                hv[r] = f2bf(fmaxf(a, 0.0f));
            }
            *(uint4*)&h0T[p * 72 + og * 8] = *(const uint4*)hv;
        }
        __syncthreads();

        const int w = t >> 6, lane = t & 63, quad = lane >> 4, l15 = lane & 15;
        const unsigned short* W1g = W1b + (size_t)s * 4096;   // [64][64]
        const unsigned short* W2g = W2b + (size_t)s * 8192;   // [128][64]

        {   // layer 2: A-frag from GLOBAL W1 (identical bytes to LDS-staged)
            #pragma unroll
            for (int ni = 0; ni < 2; ++ni) {
                floatx4 acc = (floatx4){0.f, 0.f, 0.f, 0.f};
                #pragma unroll
                for (int k0 = 0; k0 < 2; ++k0) {
                    short8 aF = *(const short8*)(W1g + (w * 16 + l15) * 64 +
                                                 k0 * 32 + quad * 8);
                    short8 bF = *(const short8*)&h0T[(ni * 16 + l15) * 72 + k0 * 32 + quad * 8];
                    acc = __builtin_amdgcn_mfma_f32_16x16x32_bf16(aF, bF, acc, 0, 0, 0);
                }
                const int m0 = w * 16 + quad * 4;
                const int p = ni * 16 + l15;
                ushort4 pk;
                pk.x = f2bf(fmaxf(acc[0] + b1s[m0 + 0], 0.f));
                pk.y = f2bf(fmaxf(acc[1] + b1s[m0 + 1], 0.f));
                pk.z = f2bf(fmaxf(acc[2] + b1s[m0 + 2], 0.f));
                pk.w = f2bf(fmaxf(acc[3] + b1s[m0 + 3], 0.f));
                *(ushort4*)&h1T[p * 72 + m0] = pk;
            }
        }
        __syncthreads();

        {   // layer 3: A-frag from GLOBAL W2
            #pragma unroll
            for (int mi = 0; mi < 2; ++mi) {
                const int m0 = (w * 2 + mi) * 16;
                #pragma unroll
                for (int ni = 0; ni < 2; ++ni) {
                    floatx4 acc = (floatx4){0.f, 0.f, 0.f, 0.f};
                    #pragma unroll
                    for (int k0 = 0; k0 < 2; ++k0) {
                        short8 aF = *(const short8*)(W2g + (m0 + l15) * 64 +
                                                     k0 * 32 + quad * 8);
                        short8 bF = *(const short8*)&h1T[(ni * 16 + l15) * 72 + k0 * 32 + quad * 8];
                        acc = __builtin_amdgcn_mfma_f32_16x16x32_bf16(aF, bF, acc, 0, 0, 0);
                    }
                    const int o2 = m0 + quad * 4;
                    const int j = j0 + ni * 16 + l15;
                    ushort4 pk;
                    pk.x = f2bf(fmaxf(acc[0] + b2s[o2 + 0], 0.f));
                    pk.y = f2bf(fmaxf(acc[1] + b2s[o2 + 1], 0.f));
                    pk.z = f2bf(fmaxf(acc[2] + b2s[o2 + 2], 0.f));
                    pk.w = f2bf(fmaxf(acc[3] + b2s[o2 + 3], 0.f));
                    *(ushort4*)&F[((size_t)b * NPTS + j) * 384 + s * 128 + o2] = pk;
                }
            }
        }
        return;
    }

    // ======================= knn path (pairs, verbatim knn19) ===============
    unsigned (*sredA)[4]   = (unsigned(*)[4])(smem);              //   32 B
    unsigned (*sredB)[4]   = (unsigned(*)[4])(smem + 32);         //   32 B
    unsigned* minSA        = (unsigned*)(smem + 64);              // 1024 B
    unsigned* minSB        = (unsigned*)(smem + 1088);            // 1024 B
    unsigned long long* CA = (unsigned long long*)(smem + 2112);  // 2048 B
    unsigned long long* CB = (unsigned long long*)(smem + 4160);  // 2048 B
    unsigned* ccnt2        = (unsigned*)(smem + 6208);            //    8 B

    const int wid = t >> 6, lane = t & 63;
    const int pr = grp * 16 + (rr - 3);      // 0..8191 = b*2048 + pair
    const int b  = pr >> 11;
    const int qa = ((pr & 2047) << 1);
    const int qb = qa + 1;
    const float4* P = pts4 + ((size_t)b << 12);
    const float4 sA = P[qa];
    const float4 sB = P[qb];

    if (t < 2) ccnt2[t] = 0u;
    CA[t] = 0xFFFFFFFFFFFFFFFFULL;           // pad for fixed-64 rank (B1 orders)
    CB[t] = 0xFFFFFFFFFFFFFFFFULL;

    unsigned kA[16], kB[16];
    #pragma unroll
    for (int g = 0; g < 4; ++g) {
        float4 c0 = P[((g * 4 + 0) << 8) + t];
        float4 c1 = P[((g * 4 + 1) << 8) + t];
        float4 c2 = P[((g * 4 + 2) << 8) + t];
        float4 c3 = P[((g * 4 + 3) << 8) + t];
        float dA0 = (sA.w + c0.w) - 2.0f * (sA.x * c0.x + sA.y * c0.y + sA.z * c0.z);
        float dA1 = (sA.w + c1.w) - 2.0f * (sA.x * c1.x + sA.y * c1.y + sA.z * c1.z);
        float dA2 = (sA.w + c2.w) - 2.0f * (sA.x * c2.x + sA.y * c2.y + sA.z * c2.z);
        float dA3 = (sA.w + c3.w) - 2.0f * (sA.x * c3.x + sA.y * c3.y + sA.z * c3.z);
        float dB0 = (sB.w + c0.w) - 2.0f * (sB.x * c0.x + sB.y * c0.y + sB.z * c0.z);
        float dB1 = (sB.w + c1.w) - 2.0f * (sB.x * c1.x + sB.y * c1.y + sB.z * c1.z);
        float dB2 = (sB.w + c2.w) - 2.0f * (sB.x * c2.x + sB.y * c2.y + sB.z * c2.z);
        float dB3 = (sB.w + c3.w) - 2.0f * (sB.x * c3.x + sB.y * c3.y + sB.z * c3.z);
        unsigned uA0 = __float_as_uint(dA0), uA1 = __float_as_uint(dA1);
        unsigned uA2 = __float_as_uint(dA2), uA3 = __float_as_uint(dA3);
        unsigned uB0 = __float_as_uint(dB0), uB1 = __float_as_uint(dB1);
        unsigned uB2 = __float_as_uint(dB2), uB3 = __float_as_uint(dB3);
        kA[g * 4 + 0] = uA0 ^ (((unsigned)((int)uA0 >> 31)) | 0x80000000u);
        kA[g * 4 + 1] = uA1 ^ (((unsigned)((int)uA1 >> 31)) | 0x80000000u);
        kA[g * 4 + 2] = uA2 ^ (((unsigned)((int)uA2 >> 31)) | 0x80000000u);
        kA[g * 4 + 3] = uA3 ^ (((unsigned)((int)uA3 >> 31)) | 0x80000000u);
        kB[g * 4 + 0] = uB0 ^ (((unsigned)((int)uB0 >> 31)) | 0x80000000u);
        kB[g * 4 + 1] = uB1 ^ (((unsigned)((int)uB1 >> 31)) | 0x80000000u);
        kB[g * 4 + 2] = uB2 ^ (((unsigned)((int)uB2 >> 31)) | 0x80000000u);
        kB[g * 4 + 3] = uB3 ^ (((unsigned)((int)uB3 >> 31)) | 0x80000000u);
    }

    unsigned tmA = kA[0], tmB = kB[0];
    #pragma unroll
    for (int r = 1; r < 16; ++r) {
        tmA = (kA[r] < tmA) ? kA[r] : tmA;
        tmB = (kB[r] < tmB) ? kB[r] : tmB;
    }
    minSA[t] = tmA;
    minSB[t] = tmB;
    __syncthreads();                                   // B1

    unsigned mA = minSA[lane], mB = minSB[lane];
    {
        unsigned a1 = minSA[lane + 64], a2 = minSA[lane + 128], a3 = minSA[lane + 192];
        unsigned b1 = minSB[lane + 64], b2 = minSB[lane + 128], b3 = minSB[lane + 192];
        mA = (a1 < mA) ? a1 : mA;  a2 = (a3 < a2) ? a3 : a2;  mA = (a2 < mA) ? a2 : mA;
        mB = (b1 < mB) ? b1 : mB;  b2 = (b3 < b2) ? b3 : b2;  mB = (b2 < mB) ? b2 : mB;
    }

    const unsigned msA = mA >> 16, msB = mB >> 16;
    unsigned loA = 0u, hiA = 0xFFFFu, loB = 0u, hiB = 0xFFFFu;
    for (int i = 0; i < 16; ++i) {
        const unsigned midA = (loA + hiA) >> 1;
        const unsigned midB = (loB + hiB) >> 1;
        const unsigned cA = (unsigned)__popcll(__ballot(msA <= midA));
        const unsigned cB = (unsigned)__popcll(__ballot(msB <= midB));
        if (cA >= 33u) hiA = midA; else loA = midA + 1u;
        if (cB >= 33u) hiB = midB; else loB = midB + 1u;
    }
    const unsigned thrA = (hiA << 16) | 0xFFFFu;
    const unsigned thrB = (hiB << 16) | 0xFFFFu;

    #pragma unroll
    for (int r = 0; r < 16; ++r) {
        if (kA[r] <= thrA) {
            unsigned p = atomicAdd(&ccnt2[0], 1u);
            if (p < 256u)
                CA[p] = ((unsigned long long)kA[r] << 32) | (unsigned)((r << 8) + t);
        }
        if (kB[r] <= thrB) {
            unsigned p = atomicAdd(&ccnt2[1], 1u);
            if (p < 256u)
                CB[p] = ((unsigned long long)kB[r] << 32) | (unsigned)((r << 8) + t);
        }
    }
    __syncthreads();                                   // B2

    int ncA = (int)ccnt2[0];
    int ncB = (int)ccnt2[1];
    bool fell_back = false;
    if (ncA > 256 || ncB > 256) {
        fell_back = true;
        if (t < 2) ccnt2[t] = 0u;
        int pp = 0;
        auto countLE2 = [&](unsigned ta, unsigned tb, unsigned& ga, unsigned& gb) {
            unsigned ca = 0, cb = 0;
            #pragma unroll
            for (int r = 0; r < 16; ++r) {
                ca += (unsigned)__popcll(__ballot(kA[r] <= ta));
                cb += (unsigned)__popcll(__ballot(kB[r] <= tb));
            }
            if (lane == 0) { sredA[pp & 1][wid] = ca; sredB[pp & 1][wid] = cb; }
            __syncthreads();
            ga = sredA[pp & 1][0] + sredA[pp & 1][1] +
                 sredA[pp & 1][2] + sredA[pp & 1][3];
            gb = sredB[pp & 1][0] + sredB[pp & 1][1] +
                 sredB[pp & 1][2] + sredB[pp & 1][3];
            ++pp;
        };
        unsigned lo2A = 0x100u, hi2A = 0x1FEu, cHiA = 4096u;
        unsigned lo2B = 0x100u, hi2B = 0x1FEu, cHiB = 4096u;
        for (int it = 0; it < 8; ++it) {
            const unsigned mAe = (lo2A + hi2A) >> 1;
            const unsigned mBe = (lo2B + hi2B) >> 1;
            unsigned ga, gb;
            countLE2((mAe << 23) | 0x7FFFFFu, (mBe << 23) | 0x7FFFFFu, ga, gb);
            if (ga >= 33u) { hi2A = mAe; cHiA = ga; } else lo2A = mAe + 1u;
            if (gb >= 33u) { hi2B = mBe; cHiB = gb; } else lo2B = mBe + 1u;
        }
        unsigned loKA = lo2A << 23, hiKA = (lo2A << 23) | 0x7FFFFFu, cFA = cHiA;
        unsigned loKB = lo2B << 23, hiKB = (lo2B << 23) | 0x7FFFFFu, cFB = cHiB;
        while (((cFA > 256u) && (loKA < hiKA)) || ((cFB > 256u) && (loKB < hiKB))) {
            const bool nAx = (cFA > 256u) && (loKA < hiKA);
            const bool nBx = (cFB > 256u) && (loKB < hiKB);
            const unsigned mAk = nAx ? (loKA + ((hiKA - loKA) >> 1)) : hiKA;
            const unsigned mBk = nBx ? (loKB + ((hiKB - loKB) >> 1)) : hiKB;
            unsigned ga, gb;
            countLE2(mAk, mBk, ga, gb);
            if (nAx) { if (ga >= 33u) { hiKA = mAk; cFA = ga; } else loKA = mAk + 1u; }
            if (nBx) { if (gb >= 33u) { hiKB = mBk; cFB = gb; } else loKB = mBk + 1u; }
        }
        const unsigned tFA = hiKA, tFB = hiKB;
        #pragma unroll
        for (int r = 0; r < 16; ++r) {
            if (kA[r] <= tFA) {
                unsigned p = atomicAdd(&ccnt2[0], 1u);
                if (p < 256u)
                    CA[p] = ((unsigned long long)kA[r] << 32) | (unsigned)((r << 8) + t);
            }
            if (kB[r] <= tFB) {
                unsigned p = atomicAdd(&ccnt2[1], 1u);
                if (p < 256u)
                    CB[p] = ((unsigned long long)kB[r] << 32) | (unsigned)((r << 8) + t);
            }
        }
        __syncthreads();
        ncA = (int)ccnt2[0]; if (ncA > 256) ncA = 256;
        ncB = (int)ccnt2[1]; if (ncB > 256) ncB = 256;
    }

    if (!fell_back && ncA <= 64 && ncB <= 64) {
        if (t < 64) {
            const unsigned long long me = CA[t];
            int rank = 0;
            #pragma unroll
            for (int j = 0; j < 64; ++j) rank += (CA[j] < me) ? 1 : 0;
            if (rank >= 1 && rank <= KNN)
                knn_out[((size_t)((b << 12) + qa)) * KNN + (rank - 1)] =
                    (int)(me & 0xFFFFFFFFu);
        } else if (t < 128) {
            const int tb = t - 64;
            const unsigned long long me = CB[tb];
            int rank = 0;
            #pragma unroll
            for (int j = 0; j < 64; ++j) rank += (CB[j] < me) ? 1 : 0;
            if (rank >= 1 && rank <= KNN)
                knn_out[((size_t)((b << 12) + qb)) * KNN + (rank - 1)] =
                    (int)(me & 0xFFFFFFFFu);
        }
    } else {
        if (t < ncA) {
            const unsigned long long me = CA[t];
            int rank = 0;
            for (int j = 0; j < ncA; ++j) rank += (CA[j] < me) ? 1 : 0;
            if (rank >= 1 && rank <= KNN)
                knn_out[((size_t)((b << 12) + qa)) * KNN + (rank - 1)] =
                    (int)(me & 0xFFFFFFFFu);
        }
        if (t < ncB) {
            const unsigned long long me = CB[t];
            int rank = 0;
            for (int j = 0; j < ncB; ++j) rank += (CB[j] < me) ? 1 : 0;
            if (rank >= 1 && rank <= KNN)
                knn_out[((size_t)((b << 12) + qb)) * KNN + (rank - 1)] =
                    (int)(me & 0xFFFFFFFFu);
        }
    }
}

// ---------------- Kernel 3: gather-max, 2 channels/lane (R10-passing) --------
__global__ __launch_bounds__(192) void maxgather_bf16(
    const unsigned short* __restrict__ F, const int* __restrict__ knn,
    unsigned short* __restrict__ pt)
{
    __shared__ int idxS[KNN];
    const int q = blockIdx.x;            // b*4096 + n
    const int b = q >> 12;
    const int t = threadIdx.x;           // channel-pair 0..191
    if (t < KNN) idxS[t] = knn[(size_t)q * KNN + t];
    __syncthreads();
    const unsigned short* Fb = F + (size_t)b * NPTS * 384 + t * 2;
    u16x2 m = (u16x2)0;
    #pragma unroll 8
    for (int k = 0; k < KNN; ++k) {
        u16x2 v = *(const u16x2*)(Fb + (size_t)idxS[k] * 384);
        m = __builtin_elementwise_max(m, v);
    }
    *(u16x2*)(pt + (size_t)q * 384 + t * 2) = m;
}

// ---------------- Kernel 4: bf16 MFMA GEMM + bias + relu (R10-passing) -------
template<int DO_ROWMAX>
__global__ __launch_bounds__(256) void gemm_bf16(
    const unsigned short* __restrict__ Wb, const unsigned short* __restrict__ Bt,
    const float* __restrict__ bias, void* __restrict__ outp,
    float* __restrict__ gfeat, int M, int K)
{
    __shared__ __align__(16) unsigned short As[128 * 40];
    __shared__ __align__(16) unsigned short Bs[128 * 40];
    __shared__ float biasS[128];
    __shared__ int redI[128];

    const int t = threadIdx.x;
    const int b = blockIdx.z;
    const int m0 = blockIdx.x * 128;
    const int n0 = blockIdx.y * 128;
    if (t < 128) biasS[t] = bias[m0 + t];
    if (DO_ROWMAX && t < 128) redI[t] = 0;

    const int wave = t >> 6, lane = t & 63, quad = lane >> 4, l15 = lane & 15;
    const int wr = wave >> 1, wc = wave & 1;

    const int am = t & 127, akh = t >> 7;
    const unsigned short* Wp = Wb + (size_t)(m0 + am) * K + akh * 16;
    const int bn = t >> 2, bq = t & 3;
    const unsigned short* Bp = Bt + ((size_t)b * NPTS + n0) * K;

    floatx4 acc[16];
    #pragma unroll
    for (int i = 0; i < 16; ++i) acc[i] = (floatx4){0.f, 0.f, 0.f, 0.f};

    const int nk = K >> 5;
    for (int kt = 0; kt < nk; ++kt) {
        const int k0 = kt << 5;
        uint4 av0 = *(const uint4*)(Wp + k0);
        uint4 av1 = *(const uint4*)(Wp + k0 + 8);
        uint4 bv0 = *(const uint4*)(Bp + (size_t)bn * K + k0 + bq * 8);
        uint4 bv1 = *(const uint4*)(Bp + (size_t)(bn + 64) * K + k0 + bq * 8);
        __syncthreads();
        {
            uint4* dst = (uint4*)&As[am * 40 + akh * 16];
            dst[0] = av0;
            dst[1] = av1;
            *(uint4*)&Bs[bn * 40 + bq * 8] = bv0;
            *(uint4*)&Bs[(bn + 64) * 40 + bq * 8] = bv1;
        }
        __syncthreads();
        short8 af[4], bfv[4];
        #pragma unroll
        for (int i = 0; i < 4; ++i)
            af[i] = *(const short8*)&As[(wr * 64 + i * 16 + l15) * 40 + quad * 8];
        #pragma unroll
        for (int j = 0; j < 4; ++j)
            bfv[j] = *(const short8*)&Bs[(wc * 64 + j * 16 + l15) * 40 + quad * 8];
        #pragma unroll
        for (int i = 0; i < 4; ++i)
            #pragma unroll
            for (int j = 0; j < 4; ++j)
                acc[i * 4 + j] = __builtin_amdgcn_mfma_f32_16x16x32_bf16(
                    af[i], bfv[j], acc[i * 4 + j], 0, 0, 0);
    }

    #pragma unroll
    for (int i = 0; i < 4; ++i) {
        const int mbase = wr * 64 + i * 16 + quad * 4;
        float rm0 = 0.f, rm1 = 0.f, rm2 = 0.f, rm3 = 0.f;
        #pragma unroll
        for (int j = 0; j < 4; ++j) {
            const int n = n0 + wc * 64 + j * 16 + l15;
            float v0 = fmaxf(acc[i * 4 + j][0] + biasS[mbase + 0], 0.f);
            float v1 = fmaxf(acc[i * 4 + j][1] + biasS[mbase + 1], 0.f);
            float v2 = fmaxf(acc[i * 4 + j][2] + biasS[mbase + 2], 0.f);
            float v3 = fmaxf(acc[i * 4 + j][3] + biasS[mbase + 3], 0.f);
            if (DO_ROWMAX) {
                rm0 = fmaxf(rm0, v0); rm1 = fmaxf(rm1, v1);
                rm2 = fmaxf(rm2, v2); rm3 = fmaxf(rm3, v3);
            }
            ushort4 pk;
            pk.x = f2bf(v0); pk.y = f2bf(v1); pk.z = f2bf(v2); pk.w = f2bf(v3);
            *(ushort4*)((unsigned short*)outp +
                        ((size_t)b * NPTS + n) * M + m0 + mbase) = pk;
        }
        if (DO_ROWMAX) {
            atomicMax(&redI[mbase + 0], __float_as_int(rm0));
            atomicMax(&redI[mbase + 1], __float_as_int(rm1));
            atomicMax(&redI[mbase + 2], __float_as_int(rm2));
            atomicMax(&redI[mbase + 3], __float_as_int(rm3));
        }
    }
    if (DO_ROWMAX) {
        __syncthreads();
        if (t < 128)
            atomicMax((int*)&gfeat[(size_t)b * 1024 + m0 + t], redI[t]);
    }
}

// ---------------- Kernel 5: fused head v2 — direct-global A-fragments --------
// At 256 blocks = 1 block/CU the per-k-tile barrier drains are un-hidden.
// Wb2/Wb3 A-rows have ZERO cross-wave reuse (each row consumed by exactly one
// wave), so As staging was pure overhead: read A-fragments directly from
// global (L2-hot, identical bytes). First gemm keeps Bs staging (4x cross-wave
// reuse) with its 2 barriers; second gemm needs NO per-iteration barriers
// (H read-only after one post-write barrier). Removes 64 barrier drains +
// all As LDS traffic. Output math identical to the R12-passing version.
__global__ __launch_bounds__(256) void fused_head(
    const unsigned short* __restrict__ Wb2, const unsigned short* __restrict__ Wb3,
    const float* __restrict__ mb0, const float* __restrict__ mb1,
    const unsigned short* __restrict__ gft, float* __restrict__ outp)
{
    __shared__ __align__(16) unsigned short Bs[64 * 40];
    __shared__ __align__(16) unsigned short H[64 * 264];
    __shared__ float b0s[256];
    __shared__ float b1s[128];

    const int t = threadIdx.x;
    const int n0 = blockIdx.x * 64;
    const int b = blockIdx.y;
    b0s[t] = mb0[t];
    if (t < 128) b1s[t] = mb1[t];

    const int wave = t >> 6, lane = t & 63, quad = lane >> 4, l15 = lane & 15;

    const int bn = t >> 2, bq = t & 3;
    const unsigned short* Bp = gft + ((size_t)b * NPTS + n0) * 1024;

    floatx4 acc[16];
    #pragma unroll
    for (int i = 0; i < 16; ++i) acc[i] = (floatx4){0.f, 0.f, 0.f, 0.f};

    for (int kt = 0; kt < 32; ++kt) {
        const int k0 = kt << 5;
        uint4 bv = *(const uint4*)(Bp + (size_t)bn * 1024 + k0 + bq * 8);
        __syncthreads();
        *(uint4*)&Bs[bn * 40 + bq * 8] = bv;
        __syncthreads();
        short8 af[4], bfv[4];
        #pragma unroll
        for (int i = 0; i < 4; ++i)
            af[i] = *(const short8*)(Wb2 +
                (size_t)(wave * 64 + i * 16 + l15) * 1024 + k0 + quad * 8);
        #pragma unroll
        for (int j = 0; j < 4; ++j)
            bfv[j] = *(const short8*)&Bs[(j * 16 + l15) * 40 + quad * 8];
        #pragma unroll
        for (int i = 0; i < 4; ++i)
            #pragma unroll
            for (int j = 0; j < 4; ++j)
                acc[i * 4 + j] = __builtin_amdgcn_mfma_f32_16x16x32_bf16(
                    af[i], bfv[j], acc[i * 4 + j], 0, 0, 0);
    }
    #pragma unroll
    for (int i = 0; i < 4; ++i) {
        const int mbase = wave * 64 + i * 16 + quad * 4;
        #pragma unroll
        for (int j = 0; j < 4; ++j) {
            const int nl = j * 16 + l15;
            ushort4 pk;
            pk.x = f2bf(fmaxf(acc[i * 4 + j][0] + b0s[mbase + 0], 0.f));
            pk.y = f2bf(fmaxf(acc[i * 4 + j][1] + b0s[mbase + 1], 0.f));
            pk.z = f2bf(fmaxf(acc[i * 4 + j][2] + b0s[mbase + 2], 0.f));
            pk.w = f2bf(fmaxf(acc[i * 4 + j][3] + b0s[mbase + 3], 0.f));
            *(ushort4*)&H[nl * 264 + mbase] = pk;
        }
    }
    __syncthreads();                       // H complete before cross-wave reads

    floatx4 acc2[8];
    #pragma unroll
    for (int i = 0; i < 8; ++i) acc2[i] = (floatx4){0.f, 0.f, 0.f, 0.f};

    for (int kt = 0; kt < 8; ++kt) {       // no barriers: H is read-only here
        const int k0 = kt << 5;
        short8 af2[2], bf2[4];
        #pragma unroll
        for (int i = 0; i < 2; ++i)
            af2[i] = *(const short8*)(Wb3 +
                (size_t)(wave * 32 + i * 16 + l15) * 256 + k0 + quad * 8);
        #pragma unroll
        for (int j = 0; j < 4; ++j)
            bf2[j] = *(const short8*)&H[(j * 16 + l15) * 264 + k0 + quad * 8];
        #pragma unroll
        for (int i = 0; i < 2; ++i)
            #pragma unroll
            for (int j = 0; j < 4; ++j)
                acc2[i * 4 + j] = __builtin_amdgcn_mfma_f32_16x16x32_bf16(
                    af2[i], bf2[j], acc2[i * 4 + j], 0, 0, 0);
    }
    #pragma unroll
    for (int i = 0; i < 2; ++i) {
        const int m2 = wave * 32 + i * 16 + quad * 4;
        #pragma unroll
        for (int j = 0; j < 4; ++j) {
            const int n = n0 + j * 16 + l15;
            float* o = outp + ((size_t)b * 128 + m2) * NPTS + n;
            o[0 * NPTS] = fmaxf(acc2[i * 4 + j][0] + b1s[m2 + 0], 0.f);
            o[1 * NPTS] = fmaxf(acc2[i * 4 + j][1] + b1s[m2 + 1], 0.f);
            o[2 * NPTS] = fmaxf(acc2[i * 4 + j][2] + b1s[m2 + 2], 0.f);
            o[3 * NPTS] = fmaxf(acc2[i * 4 + j][3] + b1s[m2 + 3], 0.f);
        }
    }
}

extern "C" void kernel_launch(void* const* d_in, const int* in_sizes, int n_in,
                              void* d_out, int out_size, void* d_ws, size_t ws_size,
                              hipStream_t stream)
{
    const float* x   = (const float*)d_in[0];
    const float* sW0 = (const float*)d_in[1];
    const float* sb0 = (const float*)d_in[2];
    const float* sW1 = (const float*)d_in[3];
    const float* sb1 = (const float*)d_in[4];
    const float* sW2 = (const float*)d_in[5];
    const float* sb2 = (const float*)d_in[6];
    const float* gW0 = (const float*)d_in[7];
    const float* gb0 = (const float*)d_in[8];
    const float* gW1 = (const float*)d_in[9];
    const float* gb1 = (const float*)d_in[10];
    const float* mW0 = (const float*)d_in[11];
    const float* mb0 = (const float*)d_in[12];
    const float* mW1 = (const float*)d_in[13];
    const float* mb1 = (const float*)d_in[14];
    float* outp = (float*)d_out;

    char* ws = (char*)d_ws;
    int*            idx     = (int*)(ws);                        // 2 MB
    float4*         pts4    = (float4*)(ws + 2097152u);          // 256 KB
    unsigned short* Wb0     = (unsigned short*)(ws + 2359296u);  // 192 KB  gW0 bf16
    unsigned short* Wb1     = (unsigned short*)(ws + 2555904u);  // 512 KB  gW1 bf16
    unsigned short* Wb2     = (unsigned short*)(ws + 3080192u);  // 512 KB  mW0 bf16
    unsigned short* Wb3     = (unsigned short*)(ws + 3604480u);  // 64 KB   mW1 bf16
    unsigned short* Wb4     = (unsigned short*)(ws + 3670016u);  // 24 KB   sW1 bf16
    unsigned short* Wb5     = (unsigned short*)(ws + 3694592u);  // 48 KB   sW2 bf16
    unsigned short* F       = (unsigned short*)(ws + 4194304u);  // 12.6 MB [b][n][384] bf16
    unsigned short* point_t = (unsigned short*)(ws + 18874368u); // 12.6 MB [b][n][384] bf16
    unsigned short* gf0t    = (unsigned short*)(ws + 33554432u); // 8.4 MB  [b][n][256] bf16
    unsigned short* gft     = (unsigned short*)(ws + 50331648u); // 33.6 MB [b][n][1024] bf16

    prep_all<<<dim3(2768), dim3(256), 0, stream>>>(
        x, pts4, gW0, gW1, mW0, mW1, sW1, sW2, Wb0, Wb1, Wb2, Wb3, Wb4, Wb5);
    knn_pm_fused<<<dim3(9728), dim3(256), 0, stream>>>(
        pts4, idx, x, sW0, sb0, Wb4, sb1, Wb5, sb2, F);
    maxgather_bf16<<<dim3(16384), dim3(192), 0, stream>>>(F, idx, point_t);
    gemm_bf16<0><<<dim3(2, 32, 4), dim3(256), 0, stream>>>(
        Wb0, point_t, gb0, gf0t, nullptr, 256, 384);
    gemm_bf16<1><<<dim3(8, 32, 4), dim3(256), 0, stream>>>(
        Wb1, gf0t, gb1, gft, outp, 1024, 256);
    fused_head<<<dim3(64, 4), dim3(256), 0, stream>>>(
        Wb2, Wb3, mb0, mb1, gft, outp + 4096);
}